// Round 1
// baseline (356.330 us; speedup 1.0000x reference)
//
#include <hip/hip_runtime.h>
#include <cstdint>

// ---------------------------------------------------------------------------
// EncoderLayer: x -> MHA(naive ref, flash impl) -> +res,LN -> FFN -> +res,LN
// B=2, S=2048, D=768, H=12, Dk=64, Dff=3072. fp32 in/out, bf16 MFMA internal.
// ---------------------------------------------------------------------------

typedef unsigned short u16;
typedef __attribute__((ext_vector_type(4))) float f32x4;
typedef __attribute__((ext_vector_type(8))) short s16x8;   // 8 bf16 = 4 VGPRs (MFMA A/B frag)
typedef __attribute__((ext_vector_type(4))) u16  u16x4;

#define AS1 __attribute__((address_space(1)))
#define AS3 __attribute__((address_space(3)))

__device__ __forceinline__ u16 f2b(float f) {            // fp32 -> bf16 RNE
  union { float f; unsigned u; } v; v.f = f;
  unsigned r = v.u + 0x7FFFu + ((v.u >> 16) & 1u);
  return (u16)(r >> 16);
}

// async global->LDS, 16B per lane; LDS dest is wave-uniform base + lane*16
__device__ __forceinline__ void gl_lds16(const void* g, void* lds_uniform_base) {
  __builtin_amdgcn_global_load_lds((const AS1 void*)g, (AS3 void*)lds_uniform_base, 16, 0, 0);
}

__device__ __forceinline__ f32x4 mfma16(s16x8 a, s16x8 b, f32x4 c) {
  return __builtin_amdgcn_mfma_f32_16x16x32_bf16(a, b, c, 0, 0, 0);
}

// ---------------------------------------------------------------------------
// small conversion kernels (run every call; no caching allowed)
// ---------------------------------------------------------------------------

// fp32 (K,N) -> bf16 transposed (N,K), 32x32 LDS tiles, K%32==0, N%32==0
__global__ __launch_bounds__(256) void transpose_conv(const float* __restrict__ W,
                                                      u16* __restrict__ Wt, int K, int N) {
  __shared__ float tile[32][33];
  int n0 = blockIdx.x * 32, k0 = blockIdx.y * 32;
  int x = threadIdx.x, y = threadIdx.y;            // (32, 8)
#pragma unroll
  for (int yy = 0; yy < 32; yy += 8)
    tile[y + yy][x] = W[(size_t)(k0 + y + yy) * N + n0 + x];
  __syncthreads();
#pragma unroll
  for (int yy = 0; yy < 32; yy += 8)
    Wt[(size_t)(n0 + y + yy) * K + k0 + x] = f2b(tile[x][y + yy]);
}

// bf16 (S,64) per-head -> bf16 (64,S) per-head (V^T for the PV MFMA B-operand)
__global__ __launch_bounds__(256) void transpose_v(const u16* __restrict__ Vh,
                                                   u16* __restrict__ Vt) {
  __shared__ u16 tile[32][33];
  int bh = blockIdx.z;
  int d0 = blockIdx.x * 32, s0 = blockIdx.y * 32;
  const u16* src = Vh + (size_t)bh * 2048 * 64;
  u16* dst = Vt + (size_t)bh * 64 * 2048;
  int x = threadIdx.x, y = threadIdx.y;
#pragma unroll
  for (int yy = 0; yy < 32; yy += 8)
    tile[y + yy][x] = src[(size_t)(s0 + y + yy) * 64 + d0 + x];
  __syncthreads();
#pragma unroll
  for (int yy = 0; yy < 32; yy += 8)
    dst[(size_t)(d0 + y + yy) * 2048 + s0 + x] = tile[x][y + yy];
}

__global__ __launch_bounds__(256) void conv_bf16(const float* __restrict__ in,
                                                 u16* __restrict__ out) {
  size_t i = ((size_t)blockIdx.x * 256 + threadIdx.x) * 4;
  f32x4 v = *(const f32x4*)(in + i);
  u16x4 o;
#pragma unroll
  for (int k = 0; k < 4; ++k) o[k] = f2b(v[k]);
  *(u16x4*)(out + i) = o;
}

__global__ void concat_bias(const float* __restrict__ bq, const float* __restrict__ bk,
                            const float* __restrict__ bv, float* __restrict__ o) {
  int i = blockIdx.x * 256 + threadIdx.x;          // 9 blocks * 256 = 2304
  o[i] = (i < 768) ? bq[i] : (i < 1536) ? bk[i - 768] : bv[i - 1536];
}

// ---------------------------------------------------------------------------
// GEMM: C(M,N) = A(M,K)[bf16 rowmajor] * Bt(N,K)^T[bf16] + bias, fused epilogue
// m97 structure: 128x128 tile, BK=64, 4 waves (2x2), 64x64 per wave,
// global_load_lds width-16 staging, 16x16x32 bf16 MFMA.
// MODE 0: fp32 out;  MODE 1: relu -> bf16 out;  MODE 2: QKV head-split bf16
//         (Q pre-scaled by 0.125 = 1/sqrt(Dk), exact in bf16)
// ---------------------------------------------------------------------------
template <int MODE>
__global__ __launch_bounds__(256) void gemm_bt(const u16* __restrict__ A,
                                               const u16* __restrict__ Bt,
                                               const float* __restrict__ bias,
                                               float* __restrict__ Cf, u16* __restrict__ Cb,
                                               u16* __restrict__ Qo, u16* __restrict__ Ko,
                                               u16* __restrict__ Vo, int M, int N, int K) {
  __shared__ __align__(16) u16 lsA[128 * 64];
  __shared__ __align__(16) u16 lsB[128 * 64];
  const int tid = threadIdx.x;
  const int lane = tid & 63, wave = tid >> 6;
  const int lr = lane & 15, lh = lane >> 4;
  const int wr = wave >> 1, wc = wave & 1;
  const int m0 = blockIdx.y * 128;
  const int n0 = blockIdx.x * 128;

  f32x4 acc[4][4];
#pragma unroll
  for (int i = 0; i < 4; ++i)
#pragma unroll
    for (int j = 0; j < 4; ++j) acc[i][j] = f32x4{0.f, 0.f, 0.f, 0.f};

  const size_t aBase = (size_t)m0 * K;
  const size_t bBase = (size_t)n0 * K;

  for (int kt = 0; kt < K; kt += 64) {
    // stage A,B tiles: linear [row][k] layout, 128B/row, 4 issues of 16B/thread
#pragma unroll
    for (int i = 0; i < 4; ++i) {
      int byteoff = i * 4096 + tid * 16;
      int row = byteoff >> 7;
      int cole = (byteoff & 127) >> 1;
      int ldsOff = i * 4096 + wave * 1024;         // wave-uniform LDS base
      gl_lds16(A + aBase + (size_t)row * K + kt + cole, (char*)lsA + ldsOff);
      gl_lds16(Bt + bBase + (size_t)row * K + kt + cole, (char*)lsB + ldsOff);
    }
    __syncthreads();
    const u16* pa = lsA + (wr * 64 + lr) * 64 + lh * 8;
    const u16* pb = lsB + (wc * 64 + lr) * 64 + lh * 8;
#pragma unroll
    for (int ks = 0; ks < 2; ++ks) {
      s16x8 a[4], b[4];
#pragma unroll
      for (int i = 0; i < 4; ++i) {
        a[i] = *(const s16x8*)(pa + i * 16 * 64 + ks * 32);
        b[i] = *(const s16x8*)(pb + i * 16 * 64 + ks * 32);
      }
#pragma unroll
      for (int i = 0; i < 4; ++i)
#pragma unroll
        for (int j = 0; j < 4; ++j) acc[i][j] = mfma16(a[i], b[j], acc[i][j]);
    }
    __syncthreads();
  }

  // epilogue: D layout col=lane&15, row=(lane>>4)*4+reg  [guide §3, m89-verified]
#pragma unroll
  for (int i = 0; i < 4; ++i) {
    int growb = m0 + wr * 64 + i * 16 + lh * 4;
#pragma unroll
    for (int j = 0; j < 4; ++j) {
      int col = n0 + wc * 64 + j * 16 + lr;
      float bv = bias[col];
#pragma unroll
      for (int q = 0; q < 4; ++q) {
        int grow = growb + q;
        float v = acc[i][j][q] + bv;
        if (MODE == 0) {
          Cf[(size_t)grow * N + col] = v;
        } else if (MODE == 1) {
          Cb[(size_t)grow * N + col] = f2b(fmaxf(v, 0.f));
        } else {
          int sel = col / 768;
          int c2 = col - sel * 768;
          int h = c2 >> 6, d = c2 & 63;
          int b = grow >> 11, s = grow & 2047;
          size_t idx = (((size_t)(b * 12 + h)) * 2048 + s) * 64 + d;
          float vv = (sel == 0) ? v * 0.125f : v;
          u16* dst = (sel == 0) ? Qo : (sel == 1) ? Ko : Vo;
          dst[idx] = f2b(vv);
        }
      }
    }
  }
}

// ---------------------------------------------------------------------------
// Flash attention. Grid (S/128, B*H). 4 waves x 32 Q-rows, KV-tile = 64 keys.
// Q (pre-scaled 1/8) hoisted to registers; K,V^T staged via global_load_lds;
// wave-parallel online softmax (16-lane shfl_xor reduce); P via LDS for the
// PV A-operand layout.
// ---------------------------------------------------------------------------
__global__ __launch_bounds__(256) void attn(const u16* __restrict__ Qh,
                                            const u16* __restrict__ Kh,
                                            const u16* __restrict__ Vt,
                                            u16* __restrict__ ctx) {
  __shared__ __align__(16) u16 lsK[64 * 64];      // [key][dim]
  __shared__ __align__(16) u16 lsV[64 * 64];      // [dim][key]  (V^T tile)
  __shared__ __align__(16) u16 lsP[4][32 * 64];   // per-wave [qrow][key]
  const int tid = threadIdx.x, lane = tid & 63, wave = tid >> 6;
  const int lr = lane & 15, lh = lane >> 4;
  const int bh = blockIdx.y;
  const int q0 = blockIdx.x * 128 + wave * 32;
  const size_t kvBase = (size_t)bh * 2048 * 64;

  s16x8 qf[2][2];
#pragma unroll
  for (int i = 0; i < 2; ++i)
#pragma unroll
    for (int ks = 0; ks < 2; ++ks)
      qf[i][ks] = *(const s16x8*)(Qh + kvBase + (size_t)(q0 + i * 16 + lr) * 64 + ks * 32 + lh * 8);

  f32x4 oacc[2][4];
  float mrow[2][4], lrow[2][4];
#pragma unroll
  for (int i = 0; i < 2; ++i)
#pragma unroll
    for (int q = 0; q < 4; ++q) {
      mrow[i][q] = -1e30f; lrow[i][q] = 0.f;
      if (q < 4) {}
    }
#pragma unroll
  for (int i = 0; i < 2; ++i)
#pragma unroll
    for (int d = 0; d < 4; ++d) oacc[i][d] = f32x4{0.f, 0.f, 0.f, 0.f};

  for (int t0 = 0; t0 < 2048; t0 += 64) {
    // stage K tile [64][64] and V^T tile [64][64]: 8KB each, 2 issues
#pragma unroll
    for (int i = 0; i < 2; ++i) {
      int byteoff = i * 4096 + tid * 16;
      int row = byteoff >> 7;
      int cole = (byteoff & 127) >> 1;
      int ldsOff = i * 4096 + wave * 1024;
      gl_lds16(Kh + kvBase + (size_t)(t0 + row) * 64 + cole, (char*)lsK + ldsOff);
      gl_lds16(Vt + kvBase + (size_t)row * 2048 + t0 + cole, (char*)lsV + ldsOff);
    }
    __syncthreads();

    // S = Q K^T  (scores pre-scaled via Q)
    f32x4 sacc[2][4];
#pragma unroll
    for (int i = 0; i < 2; ++i)
#pragma unroll
      for (int j = 0; j < 4; ++j) sacc[i][j] = f32x4{0.f, 0.f, 0.f, 0.f};
#pragma unroll
    for (int ks = 0; ks < 2; ++ks) {
      s16x8 kb[4];
#pragma unroll
      for (int j = 0; j < 4; ++j)
        kb[j] = *(const s16x8*)(lsK + (j * 16 + lr) * 64 + ks * 32 + lh * 8);
#pragma unroll
      for (int i = 0; i < 2; ++i)
#pragma unroll
        for (int j = 0; j < 4; ++j) sacc[i][j] = mfma16(qf[i][ks], kb[j], sacc[i][j]);
    }

    // online softmax (all 64 lanes; rows live in 16-lane groups)
#pragma unroll
    for (int i = 0; i < 2; ++i) {
#pragma unroll
      for (int q = 0; q < 4; ++q) {
        float mx = fmaxf(fmaxf(sacc[i][0][q], sacc[i][1][q]),
                         fmaxf(sacc[i][2][q], sacc[i][3][q]));
        mx = fmaxf(mx, __shfl_xor(mx, 1));
        mx = fmaxf(mx, __shfl_xor(mx, 2));
        mx = fmaxf(mx, __shfl_xor(mx, 4));
        mx = fmaxf(mx, __shfl_xor(mx, 8));
        float mn = fmaxf(mrow[i][q], mx);
        float alpha = __expf(mrow[i][q] - mn);
        mrow[i][q] = mn;
        float ps = 0.f;
#pragma unroll
        for (int j = 0; j < 4; ++j) {
          float p = __expf(sacc[i][j][q] - mn);
          ps += p;
          lsP[wave][(i * 16 + lh * 4 + q) * 64 + j * 16 + lr] = f2b(p);
        }
        ps += __shfl_xor(ps, 1);
        ps += __shfl_xor(ps, 2);
        ps += __shfl_xor(ps, 4);
        ps += __shfl_xor(ps, 8);
        lrow[i][q] = lrow[i][q] * alpha + ps;
#pragma unroll
        for (int d = 0; d < 4; ++d) oacc[i][d][q] *= alpha;
      }
    }
    __syncthreads();

    // O += P V
#pragma unroll
    for (int ks = 0; ks < 2; ++ks) {
      s16x8 pa[2], vb[4];
#pragma unroll
      for (int i = 0; i < 2; ++i)
        pa[i] = *(const s16x8*)(lsP[wave] + (i * 16 + lr) * 64 + ks * 32 + lh * 8);
#pragma unroll
      for (int d = 0; d < 4; ++d)
        vb[d] = *(const s16x8*)(lsV + (d * 16 + lr) * 64 + ks * 32 + lh * 8);
#pragma unroll
      for (int i = 0; i < 2; ++i)
#pragma unroll
        for (int d = 0; d < 4; ++d) oacc[i][d] = mfma16(pa[i], vb[d], oacc[i][d]);
    }
    __syncthreads();
  }

  const int b = bh / 12, h = bh - b * 12;
#pragma unroll
  for (int i = 0; i < 2; ++i)
#pragma unroll
    for (int q = 0; q < 4; ++q) {
      float inv = 1.f / lrow[i][q];
      int s = q0 + i * 16 + lh * 4 + q;
#pragma unroll
      for (int d = 0; d < 4; ++d)
        ctx[((size_t)(b * 2048 + s)) * 768 + h * 64 + d * 16 + lr] =
            f2b(oacc[i][d][q] * inv);
    }
}

// ---------------------------------------------------------------------------
// residual + LayerNorm over 768; optionally emit bf16 copy for next GEMM
// ---------------------------------------------------------------------------
__global__ __launch_bounds__(256) void resid_ln(const float* __restrict__ xin,
                                                const float* __restrict__ yin,
                                                const float* __restrict__ gamma,
                                                const float* __restrict__ beta,
                                                float* __restrict__ outf,
                                                u16* __restrict__ outb) {
  const int row = blockIdx.x, t = threadIdx.x;
  const size_t base = (size_t)row * 768;
  float v[3], s = 0.f, s2 = 0.f;
#pragma unroll
  for (int k = 0; k < 3; ++k) {
    int c = t + k * 256;
    float val = xin[base + c] + yin[base + c];
    v[k] = val; s += val; s2 += val * val;
  }
#pragma unroll
  for (int off = 32; off > 0; off >>= 1) {
    s += __shfl_down(s, off, 64);
    s2 += __shfl_down(s2, off, 64);
  }
  __shared__ float red[8];
  int lane = t & 63, wave = t >> 6;
  if (lane == 0) { red[wave] = s; red[4 + wave] = s2; }
  __syncthreads();
  s = red[0] + red[1] + red[2] + red[3];
  s2 = red[4] + red[5] + red[6] + red[7];
  const float inv = 1.f / 768.f;
  float mu = s * inv;
  float var = fmaxf(s2 * inv - mu * mu, 0.f);
  float rs = rsqrtf(var + 1e-5f);
#pragma unroll
  for (int k = 0; k < 3; ++k) {
    int c = t + k * 256;
    float o = (v[k] - mu) * rs * gamma[c] + beta[c];
    if (outf) outf[base + c] = o;
    if (outb) outb[base + c] = f2b(o);
  }
}

// ---------------------------------------------------------------------------
extern "C" void kernel_launch(void* const* d_in, const int* in_sizes, int n_in,
                              void* d_out, int out_size, void* d_ws, size_t ws_size,
                              hipStream_t stream) {
  const float* x   = (const float*)d_in[0];
  const float* Wq  = (const float*)d_in[1];
  const float* bq  = (const float*)d_in[2];
  const float* Wk  = (const float*)d_in[3];
  const float* bk  = (const float*)d_in[4];
  const float* Wv  = (const float*)d_in[5];
  const float* bv  = (const float*)d_in[6];
  const float* Wo  = (const float*)d_in[7];
  const float* bo  = (const float*)d_in[8];
  const float* W1  = (const float*)d_in[9];
  const float* b1  = (const float*)d_in[10];
  const float* W2  = (const float*)d_in[11];
  const float* b2  = (const float*)d_in[12];
  const float* g1  = (const float*)d_in[13];
  const float* be1 = (const float*)d_in[14];
  const float* g2  = (const float*)d_in[15];
  const float* be2 = (const float*)d_in[16];
  float* out = (float*)d_out;

  const int M = in_sizes[0] / 768;   // 4096 tokens
  const int B = M / 2048;            // 2

  char* ws = (char*)d_ws;
  size_t off = 0;
  auto alloc = [&](size_t bytes) -> void* {
    void* p = ws + off;
    off += (bytes + 255) & ~(size_t)255;
    return p;
  };
  u16*   Wqkv_t = (u16*)alloc((size_t)2304 * 768 * 2);
  u16*   Wo_t   = (u16*)alloc((size_t)768 * 768 * 2);
  u16*   W1_t   = (u16*)alloc((size_t)3072 * 768 * 2);
  u16*   W2_t   = (u16*)alloc((size_t)768 * 3072 * 2);
  float* bqkv   = (float*)alloc(2304 * 4);
  u16*   Xb     = (u16*)alloc((size_t)M * 768 * 2);      // reused as ctx
  u16*   Qh     = (u16*)alloc((size_t)M * 768 * 2);
  u16*   Kh     = (u16*)alloc((size_t)M * 768 * 2);
  u16*   Vh     = (u16*)alloc((size_t)M * 768 * 2);
  u16*   Vt     = (u16*)alloc((size_t)M * 768 * 2);
  float* proj   = (float*)alloc((size_t)M * 768 * 4);    // reused as ffn out
  float* x1f    = (float*)alloc((size_t)M * 768 * 4);
  u16*   x1b    = (u16*)alloc((size_t)M * 768 * 2);
  u16*   hb     = (u16*)alloc((size_t)M * 3072 * 2);
  u16*   ctx    = Xb;
  float* ffn    = proj;

  dim3 tb(32, 8);
  // weights -> bf16 transposed
  transpose_conv<<<dim3(24, 24), tb, 0, stream>>>(Wq, Wqkv_t, 768, 768);
  transpose_conv<<<dim3(24, 24), tb, 0, stream>>>(Wk, Wqkv_t + (size_t)768 * 768, 768, 768);
  transpose_conv<<<dim3(24, 24), tb, 0, stream>>>(Wv, Wqkv_t + (size_t)1536 * 768, 768, 768);
  transpose_conv<<<dim3(24, 24), tb, 0, stream>>>(Wo, Wo_t, 768, 768);
  transpose_conv<<<dim3(96, 24), tb, 0, stream>>>(W1, W1_t, 768, 3072);
  transpose_conv<<<dim3(24, 96), tb, 0, stream>>>(W2, W2_t, 3072, 768);
  concat_bias<<<9, 256, 0, stream>>>(bq, bk, bv, bqkv);
  conv_bf16<<<(M * 768) / 1024, 256, 0, stream>>>(x, Xb);

  // QKV projection (Q pre-scaled 1/8), head-split outputs
  gemm_bt<2><<<dim3(2304 / 128, M / 128), 256, 0, stream>>>(
      Xb, Wqkv_t, bqkv, nullptr, nullptr, Qh, Kh, Vh, M, 2304, 768);

  transpose_v<<<dim3(2, 64, B * 12), tb, 0, stream>>>(Vh, Vt);

  attn<<<dim3(16, B * 12), 256, 0, stream>>>(Qh, Kh, Vt, ctx);

  // output projection -> fp32
  gemm_bt<0><<<dim3(768 / 128, M / 128), 256, 0, stream>>>(
      ctx, Wo_t, bo, proj, nullptr, nullptr, nullptr, nullptr, M, 768, 768);

  resid_ln<<<M, 256, 0, stream>>>(x, proj, g1, be1, x1f, x1b);

  // FFN
  gemm_bt<1><<<dim3(3072 / 128, M / 128), 256, 0, stream>>>(
      x1b, W1_t, b1, nullptr, hb, nullptr, nullptr, nullptr, M, 3072, 768);
  gemm_bt<0><<<dim3(768 / 128, M / 128), 256, 0, stream>>>(
      hb, W2_t, b2, ffn, nullptr, nullptr, nullptr, nullptr, M, 768, 3072);

  resid_ln<<<M, 256, 0, stream>>>(x1f, ffn, g2, be2, out, nullptr);
}

// Round 2
// 312.837 us; speedup vs baseline: 1.1390x; 1.1390x over previous
//
#include <hip/hip_runtime.h>
#include <cstdint>

// ---------------------------------------------------------------------------
// EncoderLayer: x -> MHA(flash) -> +res,LN -> FFN -> +res,LN
// B=2, S=2048, D=768, H=12, Dk=64, Dff=3072. fp32 in/out, bf16 MFMA internal.
// ---------------------------------------------------------------------------

typedef unsigned short u16;
typedef __attribute__((ext_vector_type(4))) float f32x4;
typedef __attribute__((ext_vector_type(8))) short s16x8;   // 8 bf16 = 4 VGPRs
typedef __attribute__((ext_vector_type(4))) u16  u16x4;

#define AS1 __attribute__((address_space(1)))
#define AS3 __attribute__((address_space(3)))

__device__ __forceinline__ u16 f2b(float f) {            // fp32 -> bf16 RNE
  union { float f; unsigned u; } v; v.f = f;
  unsigned r = v.u + 0x7FFFu + ((v.u >> 16) & 1u);
  return (u16)(r >> 16);
}

// async global->LDS, 16B per lane; LDS dest is wave-uniform base + lane*16
__device__ __forceinline__ void gl_lds16(const void* g, void* lds_uniform_base) {
  __builtin_amdgcn_global_load_lds((const AS1 void*)g, (AS3 void*)lds_uniform_base, 16, 0, 0);
}

__device__ __forceinline__ f32x4 mfma16(s16x8 a, s16x8 b, f32x4 c) {
  return __builtin_amdgcn_mfma_f32_16x16x32_bf16(a, b, c, 0, 0, 0);
}

// ---------------------------------------------------------------------------
// small conversion kernels (run every call; no caching allowed)
// ---------------------------------------------------------------------------

__global__ __launch_bounds__(256) void transpose_conv(const float* __restrict__ W,
                                                      u16* __restrict__ Wt, int K, int N) {
  __shared__ float tile[32][33];
  int n0 = blockIdx.x * 32, k0 = blockIdx.y * 32;
  int x = threadIdx.x, y = threadIdx.y;            // (32, 8)
#pragma unroll
  for (int yy = 0; yy < 32; yy += 8)
    tile[y + yy][x] = W[(size_t)(k0 + y + yy) * N + n0 + x];
  __syncthreads();
#pragma unroll
  for (int yy = 0; yy < 32; yy += 8)
    Wt[(size_t)(n0 + y + yy) * K + k0 + x] = f2b(tile[x][y + yy]);
}

__global__ __launch_bounds__(256) void transpose_v(const u16* __restrict__ Vh,
                                                   u16* __restrict__ Vt) {
  __shared__ u16 tile[32][33];
  int bh = blockIdx.z;
  int d0 = blockIdx.x * 32, s0 = blockIdx.y * 32;
  const u16* src = Vh + (size_t)bh * 2048 * 64;
  u16* dst = Vt + (size_t)bh * 64 * 2048;
  int x = threadIdx.x, y = threadIdx.y;
#pragma unroll
  for (int yy = 0; yy < 32; yy += 8)
    tile[y + yy][x] = src[(size_t)(s0 + y + yy) * 64 + d0 + x];
  __syncthreads();
#pragma unroll
  for (int yy = 0; yy < 32; yy += 8)
    dst[(size_t)(d0 + y + yy) * 2048 + s0 + x] = tile[x][y + yy];
}

__global__ __launch_bounds__(256) void conv_bf16(const float* __restrict__ in,
                                                 u16* __restrict__ out) {
  size_t i = ((size_t)blockIdx.x * 256 + threadIdx.x) * 4;
  f32x4 v = *(const f32x4*)(in + i);
  u16x4 o;
#pragma unroll
  for (int k = 0; k < 4; ++k) o[k] = f2b(v[k]);
  *(u16x4*)(out + i) = o;
}

__global__ void concat_bias(const float* __restrict__ bq, const float* __restrict__ bk,
                            const float* __restrict__ bv, float* __restrict__ o) {
  int i = blockIdx.x * 256 + threadIdx.x;          // 9 blocks * 256 = 2304
  o[i] = (i < 768) ? bq[i] : (i < 1536) ? bk[i - 768] : bv[i - 1536];
}

// ---------------------------------------------------------------------------
// GEMM: C(M,N) = A(M,K)[bf16 rowmajor] * Bt(N,K)^T[bf16] + bias, fused epilogue
// (m97 structure, unchanged this round)
// ---------------------------------------------------------------------------
template <int MODE>
__global__ __launch_bounds__(256) void gemm_bt(const u16* __restrict__ A,
                                               const u16* __restrict__ Bt,
                                               const float* __restrict__ bias,
                                               float* __restrict__ Cf, u16* __restrict__ Cb,
                                               u16* __restrict__ Qo, u16* __restrict__ Ko,
                                               u16* __restrict__ Vo, int M, int N, int K) {
  __shared__ __align__(16) u16 lsA[128 * 64];
  __shared__ __align__(16) u16 lsB[128 * 64];
  const int tid = threadIdx.x;
  const int lane = tid & 63, wave = tid >> 6;
  const int lr = lane & 15, lh = lane >> 4;
  const int wr = wave >> 1, wc = wave & 1;
  const int m0 = blockIdx.y * 128;
  const int n0 = blockIdx.x * 128;

  f32x4 acc[4][4];
#pragma unroll
  for (int i = 0; i < 4; ++i)
#pragma unroll
    for (int j = 0; j < 4; ++j) acc[i][j] = f32x4{0.f, 0.f, 0.f, 0.f};

  const size_t aBase = (size_t)m0 * K;
  const size_t bBase = (size_t)n0 * K;

  for (int kt = 0; kt < K; kt += 64) {
#pragma unroll
    for (int i = 0; i < 4; ++i) {
      int byteoff = i * 4096 + tid * 16;
      int row = byteoff >> 7;
      int cole = (byteoff & 127) >> 1;
      int ldsOff = i * 4096 + wave * 1024;
      gl_lds16(A + aBase + (size_t)row * K + kt + cole, (char*)lsA + ldsOff);
      gl_lds16(Bt + bBase + (size_t)row * K + kt + cole, (char*)lsB + ldsOff);
    }
    __syncthreads();
    const u16* pa = lsA + (wr * 64 + lr) * 64 + lh * 8;
    const u16* pb = lsB + (wc * 64 + lr) * 64 + lh * 8;
#pragma unroll
    for (int ks = 0; ks < 2; ++ks) {
      s16x8 a[4], b[4];
#pragma unroll
      for (int i = 0; i < 4; ++i) {
        a[i] = *(const s16x8*)(pa + i * 16 * 64 + ks * 32);
        b[i] = *(const s16x8*)(pb + i * 16 * 64 + ks * 32);
      }
#pragma unroll
      for (int i = 0; i < 4; ++i)
#pragma unroll
        for (int j = 0; j < 4; ++j) acc[i][j] = mfma16(a[i], b[j], acc[i][j]);
    }
    __syncthreads();
  }

#pragma unroll
  for (int i = 0; i < 4; ++i) {
    int growb = m0 + wr * 64 + i * 16 + lh * 4;
#pragma unroll
    for (int j = 0; j < 4; ++j) {
      int col = n0 + wc * 64 + j * 16 + lr;
      float bv = bias[col];
#pragma unroll
      for (int q = 0; q < 4; ++q) {
        int grow = growb + q;
        float v = acc[i][j][q] + bv;
        if (MODE == 0) {
          Cf[(size_t)grow * N + col] = v;
        } else if (MODE == 1) {
          Cb[(size_t)grow * N + col] = f2b(fmaxf(v, 0.f));
        } else {
          int sel = col / 768;
          int c2 = col - sel * 768;
          int h = c2 >> 6, d = c2 & 63;
          int b = grow >> 11, s = grow & 2047;
          size_t idx = (((size_t)(b * 12 + h)) * 2048 + s) * 64 + d;
          float vv = (sel == 0) ? v * 0.125f : v;
          u16* dst = (sel == 0) ? Qo : (sel == 1) ? Ko : Vo;
          dst[idx] = f2b(vv);
        }
      }
    }
  }
}

// ---------------------------------------------------------------------------
// Flash attention v2. Grid (S/128, B*H), 512 threads = 8 waves x 16 Q-rows.
// KV-tile 64. Double-buffered K/V (one barrier per tile, staging overlapped
// with compute). XOR-swizzled LDS (pre-swizzled global_load_lds source +
// swizzled ds_read, rule #21). Per-wave P tile in LDS (no cross-wave barrier).
// ---------------------------------------------------------------------------
__global__ __launch_bounds__(512) void attn(const u16* __restrict__ Qh,
                                            const u16* __restrict__ Kh,
                                            const u16* __restrict__ Vt,
                                            u16* __restrict__ ctx) {
  __shared__ __align__(16) u16 lsK[2][64 * 64];   // [buf][key][dim]   swizzled
  __shared__ __align__(16) u16 lsV[2][64 * 64];   // [buf][dim][key]   swizzled
  __shared__ __align__(16) u16 lsP[8][16 * 64];   // per-wave [qrow][key] swizzled
  const int tid = threadIdx.x, lane = tid & 63, wave = tid >> 6;
  const int lr = lane & 15, lh = lane >> 4;
  const int bh = blockIdx.y;
  const int q0 = blockIdx.x * 128 + wave * 16;
  const size_t kvBase = (size_t)bh * 2048 * 64;

  // staging geometry: 512 lanes x 16B = 8KB = one full [64][64] bf16 tile.
  // LDS dest is linear (tid*16); global source column is pre-swizzled so that
  // swizzled ds_reads below retrieve the right data.
  const int srow = tid >> 3;                       // 0..63
  const int scol = (((tid & 7) * 16) ^ ((srow & 7) << 4)) >> 1;  // elem offset
  const u16* kSrcBase = Kh + kvBase + (size_t)srow * 64 + scol;
  const u16* vSrcBase = Vt + kvBase + (size_t)srow * 2048 + scol;

  s16x8 qf[2];
#pragma unroll
  for (int ks = 0; ks < 2; ++ks)
    qf[ks] = *(const s16x8*)(Qh + kvBase + (size_t)(q0 + lr) * 64 + ks * 32 + lh * 8);

  f32x4 oacc[4];
  float mrow[4], lsum[4];
#pragma unroll
  for (int q = 0; q < 4; ++q) { mrow[q] = -1e30f; lsum[q] = 0.f; }
#pragma unroll
  for (int d = 0; d < 4; ++d) oacc[d] = f32x4{0.f, 0.f, 0.f, 0.f};

  // prologue stage of tile 0
  gl_lds16(kSrcBase, (char*)lsK[0] + wave * 1024);
  gl_lds16(vSrcBase, (char*)lsV[0] + wave * 1024);

  for (int it = 0; it < 32; ++it) {
    const int cur = it & 1;
    __syncthreads();   // staged[cur] landed; all waves done reading buf[cur^1]

    // K fragments (swizzled read)
    s16x8 kb[2][4];
#pragma unroll
    for (int ks = 0; ks < 2; ++ks)
#pragma unroll
      for (int j = 0; j < 4; ++j) {
        int r = j * 16 + lr;
        kb[ks][j] = *(const s16x8*)((const char*)lsK[cur] + r * 128 +
                                    ((ks * 64 + lh * 16) ^ ((r & 7) << 4)));
      }

    // overlap next tile's staging with compute
    if (it + 1 < 32) {
      gl_lds16(kSrcBase + (size_t)(it + 1) * 64 * 64, (char*)lsK[cur ^ 1] + wave * 1024);
      gl_lds16(vSrcBase + (it + 1) * 64,              (char*)lsV[cur ^ 1] + wave * 1024);
    }

    // S = Q K^T (scores pre-scaled via Q)
    f32x4 sacc[4];
#pragma unroll
    for (int j = 0; j < 4; ++j) sacc[j] = f32x4{0.f, 0.f, 0.f, 0.f};
    __builtin_amdgcn_s_setprio(1);
#pragma unroll
    for (int ks = 0; ks < 2; ++ks)
#pragma unroll
      for (int j = 0; j < 4; ++j) sacc[j] = mfma16(qf[ks], kb[ks][j], sacc[j]);
    __builtin_amdgcn_s_setprio(0);

    // online softmax: row q (local qrow = lh*4+q) spread over the 16 lr lanes
#pragma unroll
    for (int q = 0; q < 4; ++q) {
      float mx = fmaxf(fmaxf(sacc[0][q], sacc[1][q]), fmaxf(sacc[2][q], sacc[3][q]));
      mx = fmaxf(mx, __shfl_xor(mx, 1));
      mx = fmaxf(mx, __shfl_xor(mx, 2));
      mx = fmaxf(mx, __shfl_xor(mx, 4));
      mx = fmaxf(mx, __shfl_xor(mx, 8));
      float mn = fmaxf(mrow[q], mx);
      float alpha = __expf(mrow[q] - mn);
      mrow[q] = mn;
      int qrow = lh * 4 + q;
      float ps = 0.f;
#pragma unroll
      for (int j = 0; j < 4; ++j) {
        float p = __expf(sacc[j][q] - mn);
        ps += p;
        *(u16*)((char*)lsP[wave] + qrow * 128 +
                (((j * 16 + lr) * 2) ^ ((qrow & 7) << 4))) = f2b(p);
      }
      ps += __shfl_xor(ps, 1);
      ps += __shfl_xor(ps, 2);
      ps += __shfl_xor(ps, 4);
      ps += __shfl_xor(ps, 8);
      lsum[q] = lsum[q] * alpha + ps;
#pragma unroll
      for (int d = 0; d < 4; ++d) oacc[d][q] *= alpha;
    }

    // O += P V   (P per-wave in LDS; in-wave write->read ordering via lgkmcnt)
    __builtin_amdgcn_s_setprio(1);
#pragma unroll
    for (int ks = 0; ks < 2; ++ks) {
      s16x8 pa = *(const s16x8*)((const char*)lsP[wave] + lr * 128 +
                                 ((ks * 64 + lh * 16) ^ ((lr & 7) << 4)));
#pragma unroll
      for (int d = 0; d < 4; ++d) {
        int r = d * 16 + lr;
        s16x8 vb = *(const s16x8*)((const char*)lsV[cur] + r * 128 +
                                   ((ks * 64 + lh * 16) ^ ((r & 7) << 4)));
        oacc[d] = mfma16(pa, vb, oacc[d]);
      }
    }
    __builtin_amdgcn_s_setprio(0);
  }

  const int b = bh / 12, h = bh - b * 12;
#pragma unroll
  for (int q = 0; q < 4; ++q) {
    float inv = 1.f / lsum[q];
    int s = q0 + lh * 4 + q;
#pragma unroll
    for (int d = 0; d < 4; ++d)
      ctx[((size_t)(b * 2048 + s)) * 768 + h * 64 + d * 16 + lr] =
          f2b(oacc[d][q] * inv);
  }
}

// ---------------------------------------------------------------------------
// residual + LayerNorm over 768; optionally emit bf16 copy for next GEMM
// ---------------------------------------------------------------------------
__global__ __launch_bounds__(256) void resid_ln(const float* __restrict__ xin,
                                                const float* __restrict__ yin,
                                                const float* __restrict__ gamma,
                                                const float* __restrict__ beta,
                                                float* __restrict__ outf,
                                                u16* __restrict__ outb) {
  const int row = blockIdx.x, t = threadIdx.x;
  const size_t base = (size_t)row * 768;
  float v[3], s = 0.f, s2 = 0.f;
#pragma unroll
  for (int k = 0; k < 3; ++k) {
    int c = t + k * 256;
    float val = xin[base + c] + yin[base + c];
    v[k] = val; s += val; s2 += val * val;
  }
#pragma unroll
  for (int off = 32; off > 0; off >>= 1) {
    s += __shfl_down(s, off, 64);
    s2 += __shfl_down(s2, off, 64);
  }
  __shared__ float red[8];
  int lane = t & 63, wave = t >> 6;
  if (lane == 0) { red[wave] = s; red[4 + wave] = s2; }
  __syncthreads();
  s = red[0] + red[1] + red[2] + red[3];
  s2 = red[4] + red[5] + red[6] + red[7];
  const float inv = 1.f / 768.f;
  float mu = s * inv;
  float var = fmaxf(s2 * inv - mu * mu, 0.f);
  float rs = rsqrtf(var + 1e-5f);
#pragma unroll
  for (int k = 0; k < 3; ++k) {
    int c = t + k * 256;
    float o = (v[k] - mu) * rs * gamma[c] + beta[c];
    if (outf) outf[base + c] = o;
    if (outb) outb[base + c] = f2b(o);
  }
}

// ---------------------------------------------------------------------------
extern "C" void kernel_launch(void* const* d_in, const int* in_sizes, int n_in,
                              void* d_out, int out_size, void* d_ws, size_t ws_size,
                              hipStream_t stream) {
  const float* x   = (const float*)d_in[0];
  const float* Wq  = (const float*)d_in[1];
  const float* bq  = (const float*)d_in[2];
  const float* Wk  = (const float*)d_in[3];
  const float* bk  = (const float*)d_in[4];
  const float* Wv  = (const float*)d_in[5];
  const float* bv  = (const float*)d_in[6];
  const float* Wo  = (const float*)d_in[7];
  const float* bo  = (const float*)d_in[8];
  const float* W1  = (const float*)d_in[9];
  const float* b1  = (const float*)d_in[10];
  const float* W2  = (const float*)d_in[11];
  const float* b2  = (const float*)d_in[12];
  const float* g1  = (const float*)d_in[13];
  const float* be1 = (const float*)d_in[14];
  const float* g2  = (const float*)d_in[15];
  const float* be2 = (const float*)d_in[16];
  float* out = (float*)d_out;

  const int M = in_sizes[0] / 768;   // 4096 tokens
  const int B = M / 2048;            // 2

  char* ws = (char*)d_ws;
  size_t off = 0;
  auto alloc = [&](size_t bytes) -> void* {
    void* p = ws + off;
    off += (bytes + 255) & ~(size_t)255;
    return p;
  };
  u16*   Wqkv_t = (u16*)alloc((size_t)2304 * 768 * 2);
  u16*   Wo_t   = (u16*)alloc((size_t)768 * 768 * 2);
  u16*   W1_t   = (u16*)alloc((size_t)3072 * 768 * 2);
  u16*   W2_t   = (u16*)alloc((size_t)768 * 3072 * 2);
  float* bqkv   = (float*)alloc(2304 * 4);
  u16*   Xb     = (u16*)alloc((size_t)M * 768 * 2);      // reused as ctx
  u16*   Qh     = (u16*)alloc((size_t)M * 768 * 2);
  u16*   Kh     = (u16*)alloc((size_t)M * 768 * 2);
  u16*   Vh     = (u16*)alloc((size_t)M * 768 * 2);
  u16*   Vt     = (u16*)alloc((size_t)M * 768 * 2);
  float* proj   = (float*)alloc((size_t)M * 768 * 4);    // reused as ffn out
  float* x1f    = (float*)alloc((size_t)M * 768 * 4);
  u16*   x1b    = (u16*)alloc((size_t)M * 768 * 2);
  u16*   hb     = (u16*)alloc((size_t)M * 3072 * 2);
  u16*   ctx    = Xb;
  float* ffn    = proj;

  dim3 tb(32, 8);
  transpose_conv<<<dim3(24, 24), tb, 0, stream>>>(Wq, Wqkv_t, 768, 768);
  transpose_conv<<<dim3(24, 24), tb, 0, stream>>>(Wk, Wqkv_t + (size_t)768 * 768, 768, 768);
  transpose_conv<<<dim3(24, 24), tb, 0, stream>>>(Wv, Wqkv_t + (size_t)1536 * 768, 768, 768);
  transpose_conv<<<dim3(24, 24), tb, 0, stream>>>(Wo, Wo_t, 768, 768);
  transpose_conv<<<dim3(96, 24), tb, 0, stream>>>(W1, W1_t, 768, 3072);
  transpose_conv<<<dim3(24, 96), tb, 0, stream>>>(W2, W2_t, 3072, 768);
  concat_bias<<<9, 256, 0, stream>>>(bq, bk, bv, bqkv);
  conv_bf16<<<(M * 768) / 1024, 256, 0, stream>>>(x, Xb);

  gemm_bt<2><<<dim3(2304 / 128, M / 128), 256, 0, stream>>>(
      Xb, Wqkv_t, bqkv, nullptr, nullptr, Qh, Kh, Vh, M, 2304, 768);

  transpose_v<<<dim3(2, 64, B * 12), tb, 0, stream>>>(Vh, Vt);

  attn<<<dim3(16, B * 12), 512, 0, stream>>>(Qh, Kh, Vt, ctx);

  gemm_bt<0><<<dim3(768 / 128, M / 128), 256, 0, stream>>>(
      ctx, Wo_t, bo, proj, nullptr, nullptr, nullptr, nullptr, M, 768, 768);

  resid_ln<<<M, 256, 0, stream>>>(x, proj, g1, be1, x1f, x1b);

  gemm_bt<1><<<dim3(3072 / 128, M / 128), 256, 0, stream>>>(
      x1b, W1_t, b1, nullptr, hb, nullptr, nullptr, nullptr, M, 3072, 768);
  gemm_bt<0><<<dim3(768 / 128, M / 128), 256, 0, stream>>>(
      hb, W2_t, b2, ffn, nullptr, nullptr, nullptr, nullptr, M, 768, 3072);

  resid_ln<<<M, 256, 0, stream>>>(x1f, ffn, g2, be2, out, nullptr);
}

// Round 3
// 301.093 us; speedup vs baseline: 1.1835x; 1.0390x over previous
//
#include <hip/hip_runtime.h>
#include <cstdint>

// ---------------------------------------------------------------------------
// EncoderLayer: x -> MHA(flash, KV-split) -> +res,LN -> FFN -> +res,LN
// B=2, S=2048, D=768, H=12, Dk=64, Dff=3072. fp32 in/out, bf16 MFMA internal.
// ---------------------------------------------------------------------------

typedef unsigned short u16;
typedef __attribute__((ext_vector_type(4))) float f32x4;
typedef __attribute__((ext_vector_type(8))) short s16x8;   // 8 bf16 = 4 VGPRs
typedef __attribute__((ext_vector_type(4))) u16  u16x4;

#define AS1 __attribute__((address_space(1)))
#define AS3 __attribute__((address_space(3)))

__device__ __forceinline__ u16 f2b(float f) {            // fp32 -> bf16 RNE
  union { float f; unsigned u; } v; v.f = f;
  unsigned r = v.u + 0x7FFFu + ((v.u >> 16) & 1u);
  return (u16)(r >> 16);
}

// async global->LDS, 16B per lane; LDS dest is wave-uniform base + lane*16
__device__ __forceinline__ void gl_lds16(const void* g, void* lds_uniform_base) {
  __builtin_amdgcn_global_load_lds((const AS1 void*)g, (AS3 void*)lds_uniform_base, 16, 0, 0);
}

__device__ __forceinline__ f32x4 mfma16(s16x8 a, s16x8 b, f32x4 c) {
  return __builtin_amdgcn_mfma_f32_16x16x32_bf16(a, b, c, 0, 0, 0);
}

// ---------------------------------------------------------------------------
// small conversion kernels (run every call; no caching allowed)
// ---------------------------------------------------------------------------

__global__ __launch_bounds__(256) void transpose_conv(const float* __restrict__ W,
                                                      u16* __restrict__ Wt, int K, int N) {
  __shared__ float tile[32][33];
  int n0 = blockIdx.x * 32, k0 = blockIdx.y * 32;
  int x = threadIdx.x, y = threadIdx.y;            // (32, 8)
#pragma unroll
  for (int yy = 0; yy < 32; yy += 8)
    tile[y + yy][x] = W[(size_t)(k0 + y + yy) * N + n0 + x];
  __syncthreads();
#pragma unroll
  for (int yy = 0; yy < 32; yy += 8)
    Wt[(size_t)(n0 + y + yy) * K + k0 + x] = f2b(tile[x][y + yy]);
}

__global__ __launch_bounds__(256) void transpose_v(const u16* __restrict__ Vh,
                                                   u16* __restrict__ Vt) {
  __shared__ u16 tile[32][33];
  int bh = blockIdx.z;
  int d0 = blockIdx.x * 32, s0 = blockIdx.y * 32;
  const u16* src = Vh + (size_t)bh * 2048 * 64;
  u16* dst = Vt + (size_t)bh * 64 * 2048;
  int x = threadIdx.x, y = threadIdx.y;
#pragma unroll
  for (int yy = 0; yy < 32; yy += 8)
    tile[y + yy][x] = src[(size_t)(s0 + y + yy) * 64 + d0 + x];
  __syncthreads();
#pragma unroll
  for (int yy = 0; yy < 32; yy += 8)
    dst[(size_t)(d0 + y + yy) * 2048 + s0 + x] = tile[x][y + yy];
}

__global__ __launch_bounds__(256) void conv_bf16(const float* __restrict__ in,
                                                 u16* __restrict__ out) {
  size_t i = ((size_t)blockIdx.x * 256 + threadIdx.x) * 4;
  f32x4 v = *(const f32x4*)(in + i);
  u16x4 o;
#pragma unroll
  for (int k = 0; k < 4; ++k) o[k] = f2b(v[k]);
  *(u16x4*)(out + i) = o;
}

__global__ void concat_bias(const float* __restrict__ bq, const float* __restrict__ bk,
                            const float* __restrict__ bv, float* __restrict__ o) {
  int i = blockIdx.x * 256 + threadIdx.x;          // 9 blocks * 256 = 2304
  o[i] = (i < 768) ? bq[i] : (i < 1536) ? bk[i - 768] : bv[i - 1536];
}

// ---------------------------------------------------------------------------
// GEMM: C(M,N) = A(M,K)[bf16 rowmajor] * Bt(N,K)^T[bf16] + bias, fused epilogue
// (m97 structure, unchanged this round)
// MODE 2 note: Q is pre-scaled by 0.125*log2(e) so attention works in log2
// domain (exp2 == v_exp_f32 directly).
// ---------------------------------------------------------------------------
template <int MODE>
__global__ __launch_bounds__(256) void gemm_bt(const u16* __restrict__ A,
                                               const u16* __restrict__ Bt,
                                               const float* __restrict__ bias,
                                               float* __restrict__ Cf, u16* __restrict__ Cb,
                                               u16* __restrict__ Qo, u16* __restrict__ Ko,
                                               u16* __restrict__ Vo, int M, int N, int K) {
  __shared__ __align__(16) u16 lsA[128 * 64];
  __shared__ __align__(16) u16 lsB[128 * 64];
  const int tid = threadIdx.x;
  const int lane = tid & 63, wave = tid >> 6;
  const int lr = lane & 15, lh = lane >> 4;
  const int wr = wave >> 1, wc = wave & 1;
  const int m0 = blockIdx.y * 128;
  const int n0 = blockIdx.x * 128;

  f32x4 acc[4][4];
#pragma unroll
  for (int i = 0; i < 4; ++i)
#pragma unroll
    for (int j = 0; j < 4; ++j) acc[i][j] = f32x4{0.f, 0.f, 0.f, 0.f};

  const size_t aBase = (size_t)m0 * K;
  const size_t bBase = (size_t)n0 * K;

  for (int kt = 0; kt < K; kt += 64) {
#pragma unroll
    for (int i = 0; i < 4; ++i) {
      int byteoff = i * 4096 + tid * 16;
      int row = byteoff >> 7;
      int cole = (byteoff & 127) >> 1;
      int ldsOff = i * 4096 + wave * 1024;
      gl_lds16(A + aBase + (size_t)row * K + kt + cole, (char*)lsA + ldsOff);
      gl_lds16(Bt + bBase + (size_t)row * K + kt + cole, (char*)lsB + ldsOff);
    }
    __syncthreads();
    const u16* pa = lsA + (wr * 64 + lr) * 64 + lh * 8;
    const u16* pb = lsB + (wc * 64 + lr) * 64 + lh * 8;
#pragma unroll
    for (int ks = 0; ks < 2; ++ks) {
      s16x8 a[4], b[4];
#pragma unroll
      for (int i = 0; i < 4; ++i) {
        a[i] = *(const s16x8*)(pa + i * 16 * 64 + ks * 32);
        b[i] = *(const s16x8*)(pb + i * 16 * 64 + ks * 32);
      }
#pragma unroll
      for (int i = 0; i < 4; ++i)
#pragma unroll
        for (int j = 0; j < 4; ++j) acc[i][j] = mfma16(a[i], b[j], acc[i][j]);
    }
    __syncthreads();
  }

#pragma unroll
  for (int i = 0; i < 4; ++i) {
    int growb = m0 + wr * 64 + i * 16 + lh * 4;
#pragma unroll
    for (int j = 0; j < 4; ++j) {
      int col = n0 + wc * 64 + j * 16 + lr;
      float bv = bias[col];
#pragma unroll
      for (int q = 0; q < 4; ++q) {
        int grow = growb + q;
        float v = acc[i][j][q] + bv;
        if (MODE == 0) {
          Cf[(size_t)grow * N + col] = v;
        } else if (MODE == 1) {
          Cb[(size_t)grow * N + col] = f2b(fmaxf(v, 0.f));
        } else {
          int sel = col / 768;
          int c2 = col - sel * 768;
          int h = c2 >> 6, d = c2 & 63;
          int b = grow >> 11, s = grow & 2047;
          size_t idx = (((size_t)(b * 12 + h)) * 2048 + s) * 64 + d;
          // Q scale: (1/sqrt(64)) * log2(e) -> log2-domain softmax
          float vv = (sel == 0) ? v * 0.1803368801f : v;
          u16* dst = (sel == 0) ? Qo : (sel == 1) ? Ko : Vo;
          dst[idx] = f2b(vv);
        }
      }
    }
  }
}

// ---------------------------------------------------------------------------
// Flash attention v3: KV split-K. Grid (S/128, B*H, 2). 8 waves x 16 Q-rows.
// Each block covers `ntile` KV-tiles of 64 keys, emits UNNORMALIZED partial O
// (f32) + per-row (m, l) in log2 domain. Double-buffered swizzled K/V LDS,
// one barrier per tile, defer-max rescaling (THR=11 in log2 domain).
// ---------------------------------------------------------------------------
__global__ __launch_bounds__(512) void attn(const u16* __restrict__ Qh,
                                            const u16* __restrict__ Kh,
                                            const u16* __restrict__ Vt,
                                            float* __restrict__ Op,
                                            float* __restrict__ ml,
                                            int nbh, int ntile) {
  __shared__ __align__(16) u16 lsK[2][64 * 64];   // [buf][key][dim]   swizzled
  __shared__ __align__(16) u16 lsV[2][64 * 64];   // [buf][dim][key]   swizzled
  __shared__ __align__(16) u16 lsP[8][16 * 64];   // per-wave [qrow][key] swizzled
  const int tid = threadIdx.x, lane = tid & 63, wave = tid >> 6;
  const int lr = lane & 15, lh = lane >> 4;
  const int bh = blockIdx.y, z = blockIdx.z;
  const int q0 = blockIdx.x * 128 + wave * 16;
  const size_t kvBase = (size_t)bh * 2048 * 64;
  const int tB = z * ntile;

  const int srow = tid >> 3;                       // 0..63
  const int scol = (((tid & 7) * 16) ^ ((srow & 7) << 4)) >> 1;  // elem offset
  const u16* kSrcBase = Kh + kvBase + (size_t)srow * 64 + scol;
  const u16* vSrcBase = Vt + kvBase + (size_t)srow * 2048 + scol;

  s16x8 qf[2];
#pragma unroll
  for (int ks = 0; ks < 2; ++ks)
    qf[ks] = *(const s16x8*)(Qh + kvBase + (size_t)(q0 + lr) * 64 + ks * 32 + lh * 8);

  f32x4 oacc[4];
  float mrow[4], lsum[4];
#pragma unroll
  for (int q = 0; q < 4; ++q) { mrow[q] = -1e30f; lsum[q] = 0.f; }
#pragma unroll
  for (int d = 0; d < 4; ++d) oacc[d] = f32x4{0.f, 0.f, 0.f, 0.f};

  // prologue stage of first tile
  gl_lds16(kSrcBase + (size_t)tB * 4096, (char*)lsK[0] + wave * 1024);
  gl_lds16(vSrcBase + tB * 64,           (char*)lsV[0] + wave * 1024);

  for (int it = 0; it < ntile; ++it) {
    const int cur = it & 1;
    __syncthreads();   // staged[cur] landed; all waves done reading buf[cur^1]

    // K fragments (swizzled read)
    s16x8 kb[2][4];
#pragma unroll
    for (int ks = 0; ks < 2; ++ks)
#pragma unroll
      for (int j = 0; j < 4; ++j) {
        int r = j * 16 + lr;
        kb[ks][j] = *(const s16x8*)((const char*)lsK[cur] + r * 128 +
                                    ((ks * 64 + lh * 16) ^ ((r & 7) << 4)));
      }

    // overlap next tile's staging with compute
    if (it + 1 < ntile) {
      int t = tB + it + 1;
      gl_lds16(kSrcBase + (size_t)t * 4096, (char*)lsK[cur ^ 1] + wave * 1024);
      gl_lds16(vSrcBase + t * 64,           (char*)lsV[cur ^ 1] + wave * 1024);
    }

    // S = Q K^T (log2-domain scores; scale folded into Q)
    f32x4 sacc[4];
#pragma unroll
    for (int j = 0; j < 4; ++j) sacc[j] = f32x4{0.f, 0.f, 0.f, 0.f};
    __builtin_amdgcn_s_setprio(1);
#pragma unroll
    for (int ks = 0; ks < 2; ++ks)
#pragma unroll
      for (int j = 0; j < 4; ++j) sacc[j] = mfma16(qf[ks], kb[ks][j], sacc[j]);
    __builtin_amdgcn_s_setprio(0);

    // online softmax, defer-max: only rescale when some row max grew > 2^11
    float mx[4];
    bool need = false;
#pragma unroll
    for (int q = 0; q < 4; ++q) {
      float m4 = fmaxf(fmaxf(sacc[0][q], sacc[1][q]), fmaxf(sacc[2][q], sacc[3][q]));
      m4 = fmaxf(m4, __shfl_xor(m4, 1));
      m4 = fmaxf(m4, __shfl_xor(m4, 2));
      m4 = fmaxf(m4, __shfl_xor(m4, 4));
      m4 = fmaxf(m4, __shfl_xor(m4, 8));
      mx[q] = m4;
      need = need || (m4 > mrow[q] + 11.f);
    }
    if (__any(need)) {
#pragma unroll
      for (int q = 0; q < 4; ++q) {
        float mn = fmaxf(mrow[q], mx[q]);
        float al = exp2f(mrow[q] - mn);
        mrow[q] = mn;
        lsum[q] *= al;
#pragma unroll
        for (int d = 0; d < 4; ++d) oacc[d][q] *= al;
      }
    }
#pragma unroll
    for (int q = 0; q < 4; ++q) {
      int qrow = lh * 4 + q;
      float ps = 0.f;
#pragma unroll
      for (int j = 0; j < 4; ++j) {
        float p = exp2f(sacc[j][q] - mrow[q]);
        ps += p;
        *(u16*)((char*)lsP[wave] + qrow * 128 +
                (((j * 16 + lr) * 2) ^ ((qrow & 7) << 4))) = f2b(p);
      }
      ps += __shfl_xor(ps, 1);
      ps += __shfl_xor(ps, 2);
      ps += __shfl_xor(ps, 4);
      ps += __shfl_xor(ps, 8);
      lsum[q] += ps;
    }

    // O += P V
    __builtin_amdgcn_s_setprio(1);
#pragma unroll
    for (int ks = 0; ks < 2; ++ks) {
      s16x8 pa = *(const s16x8*)((const char*)lsP[wave] + lr * 128 +
                                 ((ks * 64 + lh * 16) ^ ((lr & 7) << 4)));
#pragma unroll
      for (int d = 0; d < 4; ++d) {
        int r = d * 16 + lr;
        s16x8 vb = *(const s16x8*)((const char*)lsV[cur] + r * 128 +
                                   ((ks * 64 + lh * 16) ^ ((r & 7) << 4)));
        oacc[d] = mfma16(pa, vb, oacc[d]);
      }
    }
    __builtin_amdgcn_s_setprio(0);
  }

  // epilogue: unnormalized partial O (f32) + (m, l)
#pragma unroll
  for (int q = 0; q < 4; ++q) {
    int s = q0 + lh * 4 + q;
    size_t r = ((size_t)z * nbh + bh) * 2048 + s;
#pragma unroll
    for (int d = 0; d < 4; ++d)
      Op[r * 64 + d * 16 + lr] = oacc[d][q];
    if (lr == 0) { ml[r * 2] = mrow[q]; ml[r * 2 + 1] = lsum[q]; }
  }
}

// combine 2 KV-split partials -> ctx (bf16, [b][s][h*64+d] layout)
__global__ __launch_bounds__(256) void attn_combine(const float* __restrict__ Op,
                                                    const float* __restrict__ ml,
                                                    u16* __restrict__ ctx, int nbh) {
  size_t i = (size_t)blockIdx.x * 256 + threadIdx.x;   // nbh*2048*16 threads
  int d4 = (int)(i & 15);
  size_t rs = i >> 4;
  size_t zs = (size_t)nbh * 2048;
  float m0 = ml[rs * 2],        l0 = ml[rs * 2 + 1];
  float m1 = ml[(zs + rs) * 2], l1 = ml[(zs + rs) * 2 + 1];
  float mx = fmaxf(m0, m1);
  float a0 = exp2f(m0 - mx), a1 = exp2f(m1 - mx);
  float inv = 1.f / (l0 * a0 + l1 * a1);
  a0 *= inv; a1 *= inv;
  f32x4 o0 = *(const f32x4*)(Op + rs * 64 + d4 * 4);
  f32x4 o1 = *(const f32x4*)(Op + (zs + rs) * 64 + d4 * 4);
  int bh = (int)(rs >> 11), s = (int)(rs & 2047);
  int b = bh / 12, h = bh - b * 12;
  u16x4 r;
#pragma unroll
  for (int k = 0; k < 4; ++k) r[k] = f2b(o0[k] * a0 + o1[k] * a1);
  *(u16x4*)(ctx + ((size_t)(b * 2048 + s)) * 768 + h * 64 + d4 * 4) = r;
}

// ---------------------------------------------------------------------------
// residual + LayerNorm over 768; optionally emit bf16 copy for next GEMM
// ---------------------------------------------------------------------------
__global__ __launch_bounds__(256) void resid_ln(const float* __restrict__ xin,
                                                const float* __restrict__ yin,
                                                const float* __restrict__ gamma,
                                                const float* __restrict__ beta,
                                                float* __restrict__ outf,
                                                u16* __restrict__ outb) {
  const int row = blockIdx.x, t = threadIdx.x;
  const size_t base = (size_t)row * 768;
  float v[3], s = 0.f, s2 = 0.f;
#pragma unroll
  for (int k = 0; k < 3; ++k) {
    int c = t + k * 256;
    float val = xin[base + c] + yin[base + c];
    v[k] = val; s += val; s2 += val * val;
  }
#pragma unroll
  for (int off = 32; off > 0; off >>= 1) {
    s += __shfl_down(s, off, 64);
    s2 += __shfl_down(s2, off, 64);
  }
  __shared__ float red[8];
  int lane = t & 63, wave = t >> 6;
  if (lane == 0) { red[wave] = s; red[4 + wave] = s2; }
  __syncthreads();
  s = red[0] + red[1] + red[2] + red[3];
  s2 = red[4] + red[5] + red[6] + red[7];
  const float inv = 1.f / 768.f;
  float mu = s * inv;
  float var = fmaxf(s2 * inv - mu * mu, 0.f);
  float rs = rsqrtf(var + 1e-5f);
#pragma unroll
  for (int k = 0; k < 3; ++k) {
    int c = t + k * 256;
    float o = (v[k] - mu) * rs * gamma[c] + beta[c];
    if (outf) outf[base + c] = o;
    if (outb) outb[base + c] = f2b(o);
  }
}

// ---------------------------------------------------------------------------
extern "C" void kernel_launch(void* const* d_in, const int* in_sizes, int n_in,
                              void* d_out, int out_size, void* d_ws, size_t ws_size,
                              hipStream_t stream) {
  const float* x   = (const float*)d_in[0];
  const float* Wq  = (const float*)d_in[1];
  const float* bq  = (const float*)d_in[2];
  const float* Wk  = (const float*)d_in[3];
  const float* bk  = (const float*)d_in[4];
  const float* Wv  = (const float*)d_in[5];
  const float* bv  = (const float*)d_in[6];
  const float* Wo  = (const float*)d_in[7];
  const float* bo  = (const float*)d_in[8];
  const float* W1  = (const float*)d_in[9];
  const float* b1  = (const float*)d_in[10];
  const float* W2  = (const float*)d_in[11];
  const float* b2  = (const float*)d_in[12];
  const float* g1  = (const float*)d_in[13];
  const float* be1 = (const float*)d_in[14];
  const float* g2  = (const float*)d_in[15];
  const float* be2 = (const float*)d_in[16];
  float* out = (float*)d_out;

  const int M = in_sizes[0] / 768;   // 4096 tokens
  const int B = M / 2048;            // 2
  const int nbh = B * 12;

  char* ws = (char*)d_ws;
  size_t off = 0;
  auto alloc = [&](size_t bytes) -> void* {
    void* p = ws + off;
    off += (bytes + 255) & ~(size_t)255;
    return p;
  };
  u16*   Wqkv_t = (u16*)alloc((size_t)2304 * 768 * 2);
  u16*   Wo_t   = (u16*)alloc((size_t)768 * 768 * 2);
  u16*   W1_t   = (u16*)alloc((size_t)3072 * 768 * 2);
  u16*   W2_t   = (u16*)alloc((size_t)768 * 3072 * 2);
  float* bqkv   = (float*)alloc(2304 * 4);
  u16*   Xb     = (u16*)alloc((size_t)M * 768 * 2);      // reused as ctx
  u16*   Qh     = (u16*)alloc((size_t)M * 768 * 2);
  u16*   Kh     = (u16*)alloc((size_t)M * 768 * 2);
  u16*   Vh     = (u16*)alloc((size_t)M * 768 * 2);
  u16*   Vt     = (u16*)alloc((size_t)M * 768 * 2);
  // shared region: [attn phase] Op (2 x nbh x 2048 x 64 f32) + ml
  //                [later]      proj (M*768 f32) + x1f (M*768 f32)
  size_t opElems = (size_t)2 * nbh * 2048 * 64;
  size_t mlElems = (size_t)2 * nbh * 2048 * 2;
  size_t regionA = (opElems + mlElems) * 4;
  size_t regionB = (size_t)M * 768 * 4 * 2;
  float* region = (float*)alloc(regionA > regionB ? regionA : regionB);
  float* Op   = region;
  float* ml   = region + opElems;
  float* proj = region;                       // alive only after combine
  float* x1f  = region + (size_t)M * 768;
  u16*   x1b  = (u16*)alloc((size_t)M * 768 * 2);
  u16*   hb   = (u16*)alloc((size_t)M * 3072 * 2);
  u16*   ctx  = Xb;
  float* ffn  = proj;

  dim3 tb(32, 8);
  transpose_conv<<<dim3(24, 24), tb, 0, stream>>>(Wq, Wqkv_t, 768, 768);
  transpose_conv<<<dim3(24, 24), tb, 0, stream>>>(Wk, Wqkv_t + (size_t)768 * 768, 768, 768);
  transpose_conv<<<dim3(24, 24), tb, 0, stream>>>(Wv, Wqkv_t + (size_t)1536 * 768, 768, 768);
  transpose_conv<<<dim3(24, 24), tb, 0, stream>>>(Wo, Wo_t, 768, 768);
  transpose_conv<<<dim3(96, 24), tb, 0, stream>>>(W1, W1_t, 768, 3072);
  transpose_conv<<<dim3(24, 96), tb, 0, stream>>>(W2, W2_t, 3072, 768);
  concat_bias<<<9, 256, 0, stream>>>(bq, bk, bv, bqkv);
  conv_bf16<<<(M * 768) / 1024, 256, 0, stream>>>(x, Xb);

  gemm_bt<2><<<dim3(2304 / 128, M / 128), 256, 0, stream>>>(
      Xb, Wqkv_t, bqkv, nullptr, nullptr, Qh, Kh, Vh, M, 2304, 768);

  transpose_v<<<dim3(2, 64, nbh), tb, 0, stream>>>(Vh, Vt);

  attn<<<dim3(16, nbh, 2), 512, 0, stream>>>(Qh, Kh, Vt, Op, ml, nbh, 16);
  attn_combine<<<nbh * 128, 256, 0, stream>>>(Op, ml, ctx, nbh);

  gemm_bt<0><<<dim3(768 / 128, M / 128), 256, 0, stream>>>(
      ctx, Wo_t, bo, proj, nullptr, nullptr, nullptr, nullptr, M, 768, 768);

  resid_ln<<<M, 256, 0, stream>>>(x, proj, g1, be1, x1f, x1b);

  gemm_bt<1><<<dim3(3072 / 128, M / 128), 256, 0, stream>>>(
      x1b, W1_t, b1, nullptr, hb, nullptr, nullptr, nullptr, M, 3072, 768);
  gemm_bt<0><<<dim3(768 / 128, M / 128), 256, 0, stream>>>(
      hb, W2_t, b2, ffn, nullptr, nullptr, nullptr, nullptr, M, 768, 3072);

  resid_ln<<<M, 256, 0, stream>>>(x1f, ffn, g2, be2, out, nullptr);
}

// Round 4
// 272.509 us; speedup vs baseline: 1.3076x; 1.1049x over previous
//
#include <hip/hip_runtime.h>
#include <cstdint>

// ---------------------------------------------------------------------------
// EncoderLayer: x -> MHA(flash, KV-split, swapped-QK^T in-lane softmax)
//               -> +res,LN -> FFN -> +res,LN
// B=2, S=2048, D=768, H=12, Dk=64, Dff=3072. fp32 in/out, bf16 MFMA internal.
// ---------------------------------------------------------------------------

typedef unsigned short u16;
typedef unsigned int u32;
typedef __attribute__((ext_vector_type(4))) float f32x4;
typedef __attribute__((ext_vector_type(8))) short s16x8;   // 8 bf16 = 4 VGPRs
typedef __attribute__((ext_vector_type(4))) u16  u16x4;
typedef __attribute__((ext_vector_type(2))) u32  u32x2;

#define AS1 __attribute__((address_space(1)))
#define AS3 __attribute__((address_space(3)))

__device__ __forceinline__ u16 f2b(float f) {            // fp32 -> bf16 RNE
  union { float f; unsigned u; } v; v.f = f;
  unsigned r = v.u + 0x7FFFu + ((v.u >> 16) & 1u);
  return (u16)(r >> 16);
}

// async global->LDS, 16B per lane; LDS dest is wave-uniform base + lane*16
__device__ __forceinline__ void gl_lds16(const void* g, void* lds_uniform_base) {
  __builtin_amdgcn_global_load_lds((const AS1 void*)g, (AS3 void*)lds_uniform_base, 16, 0, 0);
}

__device__ __forceinline__ f32x4 mfma16(s16x8 a, s16x8 b, f32x4 c) {
  return __builtin_amdgcn_mfma_f32_16x16x32_bf16(a, b, c, 0, 0, 0);
}

__device__ __forceinline__ u32 cvt_pk_bf16(float lo, float hi) {
  u32 r;
  asm("v_cvt_pk_bf16_f32 %0, %1, %2" : "=v"(r) : "v"(lo), "v"(hi));
  return r;
}

// ---------------------------------------------------------------------------
// small conversion kernels (run every call; no caching allowed)
// ---------------------------------------------------------------------------

__global__ __launch_bounds__(256) void transpose_conv(const float* __restrict__ W,
                                                      u16* __restrict__ Wt, int K, int N) {
  __shared__ float tile[32][33];
  int n0 = blockIdx.x * 32, k0 = blockIdx.y * 32;
  int x = threadIdx.x, y = threadIdx.y;            // (32, 8)
#pragma unroll
  for (int yy = 0; yy < 32; yy += 8)
    tile[y + yy][x] = W[(size_t)(k0 + y + yy) * N + n0 + x];
  __syncthreads();
#pragma unroll
  for (int yy = 0; yy < 32; yy += 8)
    Wt[(size_t)(n0 + y + yy) * K + k0 + x] = f2b(tile[x][y + yy]);
}

__global__ __launch_bounds__(256) void transpose_v(const u16* __restrict__ Vh,
                                                   u16* __restrict__ Vt) {
  __shared__ u16 tile[32][33];
  int bh = blockIdx.z;
  int d0 = blockIdx.x * 32, s0 = blockIdx.y * 32;
  const u16* src = Vh + (size_t)bh * 2048 * 64;
  u16* dst = Vt + (size_t)bh * 64 * 2048;
  int x = threadIdx.x, y = threadIdx.y;
#pragma unroll
  for (int yy = 0; yy < 32; yy += 8)
    tile[y + yy][x] = src[(size_t)(s0 + y + yy) * 64 + d0 + x];
  __syncthreads();
#pragma unroll
  for (int yy = 0; yy < 32; yy += 8)
    dst[(size_t)(d0 + y + yy) * 2048 + s0 + x] = tile[x][y + yy];
}

__global__ __launch_bounds__(256) void conv_bf16(const float* __restrict__ in,
                                                 u16* __restrict__ out) {
  size_t i = ((size_t)blockIdx.x * 256 + threadIdx.x) * 4;
  f32x4 v = *(const f32x4*)(in + i);
  u16x4 o;
#pragma unroll
  for (int k = 0; k < 4; ++k) o[k] = f2b(v[k]);
  *(u16x4*)(out + i) = o;
}

__global__ void concat_bias(const float* __restrict__ bq, const float* __restrict__ bk,
                            const float* __restrict__ bv, float* __restrict__ o) {
  int i = blockIdx.x * 256 + threadIdx.x;          // 9 blocks * 256 = 2304
  o[i] = (i < 768) ? bq[i] : (i < 1536) ? bk[i - 768] : bv[i - 1536];
}

// ---------------------------------------------------------------------------
// GEMM: C(M,N) = A(M,K)[bf16 rowmajor] * Bt(N,K)^T[bf16] + bias, fused epilogue
// (m97 structure, frozen this round)
// MODE 2: QKV head-split; Q pre-scaled by 0.125*log2(e) (log2-domain softmax).
// ---------------------------------------------------------------------------
template <int MODE>
__global__ __launch_bounds__(256) void gemm_bt(const u16* __restrict__ A,
                                               const u16* __restrict__ Bt,
                                               const float* __restrict__ bias,
                                               float* __restrict__ Cf, u16* __restrict__ Cb,
                                               u16* __restrict__ Qo, u16* __restrict__ Ko,
                                               u16* __restrict__ Vo, int M, int N, int K) {
  __shared__ __align__(16) u16 lsA[128 * 64];
  __shared__ __align__(16) u16 lsB[128 * 64];
  const int tid = threadIdx.x;
  const int lane = tid & 63, wave = tid >> 6;
  const int lr = lane & 15, lh = lane >> 4;
  const int wr = wave >> 1, wc = wave & 1;
  const int m0 = blockIdx.y * 128;
  const int n0 = blockIdx.x * 128;

  f32x4 acc[4][4];
#pragma unroll
  for (int i = 0; i < 4; ++i)
#pragma unroll
    for (int j = 0; j < 4; ++j) acc[i][j] = f32x4{0.f, 0.f, 0.f, 0.f};

  const size_t aBase = (size_t)m0 * K;
  const size_t bBase = (size_t)n0 * K;

  for (int kt = 0; kt < K; kt += 64) {
#pragma unroll
    for (int i = 0; i < 4; ++i) {
      int byteoff = i * 4096 + tid * 16;
      int row = byteoff >> 7;
      int cole = (byteoff & 127) >> 1;
      int ldsOff = i * 4096 + wave * 1024;
      gl_lds16(A + aBase + (size_t)row * K + kt + cole, (char*)lsA + ldsOff);
      gl_lds16(Bt + bBase + (size_t)row * K + kt + cole, (char*)lsB + ldsOff);
    }
    __syncthreads();
    const u16* pa = lsA + (wr * 64 + lr) * 64 + lh * 8;
    const u16* pb = lsB + (wc * 64 + lr) * 64 + lh * 8;
#pragma unroll
    for (int ks = 0; ks < 2; ++ks) {
      s16x8 a[4], b[4];
#pragma unroll
      for (int i = 0; i < 4; ++i) {
        a[i] = *(const s16x8*)(pa + i * 16 * 64 + ks * 32);
        b[i] = *(const s16x8*)(pb + i * 16 * 64 + ks * 32);
      }
#pragma unroll
      for (int i = 0; i < 4; ++i)
#pragma unroll
        for (int j = 0; j < 4; ++j) acc[i][j] = mfma16(a[i], b[j], acc[i][j]);
    }
    __syncthreads();
  }

#pragma unroll
  for (int i = 0; i < 4; ++i) {
    int growb = m0 + wr * 64 + i * 16 + lh * 4;
#pragma unroll
    for (int j = 0; j < 4; ++j) {
      int col = n0 + wc * 64 + j * 16 + lr;
      float bv = bias[col];
#pragma unroll
      for (int q = 0; q < 4; ++q) {
        int grow = growb + q;
        float v = acc[i][j][q] + bv;
        if (MODE == 0) {
          Cf[(size_t)grow * N + col] = v;
        } else if (MODE == 1) {
          Cb[(size_t)grow * N + col] = f2b(fmaxf(v, 0.f));
        } else {
          int sel = col / 768;
          int c2 = col - sel * 768;
          int h = c2 >> 6, d = c2 & 63;
          int b = grow >> 11, s = grow & 2047;
          size_t idx = (((size_t)(b * 12 + h)) * 2048 + s) * 64 + d;
          // Q scale: (1/sqrt(64)) * log2(e) -> log2-domain softmax
          float vv = (sel == 0) ? v * 0.1803368801f : v;
          u16* dst = (sel == 0) ? Qo : (sel == 1) ? Ko : Vo;
          dst[idx] = f2b(vv);
        }
      }
    }
  }
}

// ---------------------------------------------------------------------------
// Flash attention v4: KV split-K, SWAPPED-operand MFMA.
// Grid (S/128, B*H, 2), 8 waves x 16 Q-rows. Per lane: one q-row (lr),
// 16 keys in-lane after S^T = mfma(K,Q). In-lane softmax (2 shfls/tile),
// cvt_pk-packed P -> 4 ds_write_b64. PV swapped: O^T = mfma(V^T, P).
// XCD-chunked block remap for K/V L2 locality.
// ---------------------------------------------------------------------------
__global__ __launch_bounds__(512) void attn(const u16* __restrict__ Qh,
                                            const u16* __restrict__ Kh,
                                            const u16* __restrict__ Vt,
                                            float* __restrict__ Op,
                                            float* __restrict__ ml,
                                            int nbh, int ntile) {
  __shared__ __align__(16) u16 lsK[2][64 * 64];   // [buf][key][dim]   swizzled
  __shared__ __align__(16) u16 lsV[2][64 * 64];   // [buf][dim][key]   swizzled
  __shared__ __align__(16) u16 lsP[8][16 * 64];   // per-wave [qrow][key] swizzled
  const int tid = threadIdx.x, lane = tid & 63, wave = tid >> 6;
  const int lr = lane & 15, lh = lane >> 4;

  // XCD-chunked remap (bijective when total%8==0): blocks sharing (bh,z)
  // land on the same XCD -> K/V served from its L2.
  int bx = blockIdx.x, bh = blockIdx.y, z = blockIdx.z;
  {
    int total = 16 * nbh * 2;
    if ((total & 7) == 0) {
      int lin = bx + 16 * (bh + nbh * z);
      int nl = (lin & 7) * (total >> 3) + (lin >> 3);
      bx = nl & 15;
      bh = (nl >> 4) % nbh;
      z = nl / (16 * nbh);
    }
  }
  const int q0 = bx * 128 + wave * 16;
  const size_t kvBase = (size_t)bh * 2048 * 64;
  const int tB = z * ntile;

  const int srow = tid >> 3;                       // 0..63
  const int scol = (((tid & 7) * 16) ^ ((srow & 7) << 4)) >> 1;  // elem offset
  const u16* kSrcBase = Kh + kvBase + (size_t)srow * 64 + scol;
  const u16* vSrcBase = Vt + kvBase + (size_t)srow * 2048 + scol;

  s16x8 qf[2];
#pragma unroll
  for (int ks = 0; ks < 2; ++ks)
    qf[ks] = *(const s16x8*)(Qh + kvBase + (size_t)(q0 + lr) * 64 + ks * 32 + lh * 8);

  // oacc[dblk] reg q = O[q0+lr][dblk*16 + lh*4 + q]  (O^T layout from swapped PV)
  f32x4 oacc[4];
  float mrow = -1e30f, lsum = 0.f;
#pragma unroll
  for (int d = 0; d < 4; ++d) oacc[d] = f32x4{0.f, 0.f, 0.f, 0.f};

  // prologue stage of first tile
  gl_lds16(kSrcBase + (size_t)tB * 4096, (char*)lsK[0] + wave * 1024);
  gl_lds16(vSrcBase + tB * 64,           (char*)lsV[0] + wave * 1024);

  for (int it = 0; it < ntile; ++it) {
    const int cur = it & 1;
    __syncthreads();   // staged[cur] landed; all waves done reading buf[cur^1]

    // K fragments (swizzled read)
    s16x8 kb[2][4];
#pragma unroll
    for (int ks = 0; ks < 2; ++ks)
#pragma unroll
      for (int j = 0; j < 4; ++j) {
        int r = j * 16 + lr;
        kb[ks][j] = *(const s16x8*)((const char*)lsK[cur] + r * 128 +
                                    ((ks * 64 + lh * 16) ^ ((r & 7) << 4)));
      }

    // overlap next tile's staging with compute
    if (it + 1 < ntile) {
      int t = tB + it + 1;
      gl_lds16(kSrcBase + (size_t)t * 4096, (char*)lsK[cur ^ 1] + wave * 1024);
      gl_lds16(vSrcBase + t * 64,           (char*)lsV[cur ^ 1] + wave * 1024);
    }

    // S^T = K Q^T : st[j] reg q = S[q0+lr][key = j*16 + lh*4 + q]
    f32x4 st[4];
#pragma unroll
    for (int j = 0; j < 4; ++j) st[j] = f32x4{0.f, 0.f, 0.f, 0.f};
    __builtin_amdgcn_s_setprio(1);
#pragma unroll
    for (int ks = 0; ks < 2; ++ks)
#pragma unroll
      for (int j = 0; j < 4; ++j) st[j] = mfma16(kb[ks][j], qf[ks], st[j]);
    __builtin_amdgcn_s_setprio(0);

    // in-lane row max over 16 keys + cross-lh combine (2 shfls)
    float mx;
    {
      float a0 = fmaxf(fmaxf(st[0][0], st[0][1]), fmaxf(st[0][2], st[0][3]));
      float a1 = fmaxf(fmaxf(st[1][0], st[1][1]), fmaxf(st[1][2], st[1][3]));
      float a2 = fmaxf(fmaxf(st[2][0], st[2][1]), fmaxf(st[2][2], st[2][3]));
      float a3 = fmaxf(fmaxf(st[3][0], st[3][1]), fmaxf(st[3][2], st[3][3]));
      mx = fmaxf(fmaxf(a0, a1), fmaxf(a2, a3));
      mx = fmaxf(mx, __shfl_xor(mx, 16));
      mx = fmaxf(mx, __shfl_xor(mx, 32));
    }
    // defer-max: rescale only when some row grew > 2^11 (log2 domain)
    if (__any(mx > mrow + 11.f)) {
      float mn = fmaxf(mrow, mx);
      float al = exp2f(mrow - mn);
      mrow = mn;
      lsum *= al;
#pragma unroll
      for (int d = 0; d < 4; ++d)
#pragma unroll
        for (int q = 0; q < 4; ++q) oacc[d][q] *= al;
    }

    // P = exp2(S - m): pack to bf16 pairs, 4x ds_write_b64 into lsP[qrow][key]
    float ps = 0.f;
#pragma unroll
    for (int j = 0; j < 4; ++j) {
      float p0 = exp2f(st[j][0] - mrow);
      float p1 = exp2f(st[j][1] - mrow);
      float p2 = exp2f(st[j][2] - mrow);
      float p3 = exp2f(st[j][3] - mrow);
      ps += (p0 + p1) + (p2 + p3);
      u32x2 pk;
      pk.x = cvt_pk_bf16(p0, p1);
      pk.y = cvt_pk_bf16(p2, p3);
      *(u32x2*)((char*)lsP[wave] + lr * 128 + ((j * 32 + lh * 8) ^ ((lr & 7) << 4))) = pk;
    }
    ps += __shfl_xor(ps, 16);
    ps += __shfl_xor(ps, 32);
    lsum += ps;

    // O^T += V^T P : oacc[dblk] = mfma(A=V^T rows=dims, B=P rows=qrows)
    __builtin_amdgcn_s_setprio(1);
#pragma unroll
    for (int ks = 0; ks < 2; ++ks) {
      s16x8 pa = *(const s16x8*)((const char*)lsP[wave] + lr * 128 +
                                 ((ks * 64 + lh * 16) ^ ((lr & 7) << 4)));
#pragma unroll
      for (int d = 0; d < 4; ++d) {
        int r = d * 16 + lr;
        s16x8 vb = *(const s16x8*)((const char*)lsV[cur] + r * 128 +
                                   ((ks * 64 + lh * 16) ^ ((r & 7) << 4)));
        oacc[d] = mfma16(vb, pa, oacc[d]);
      }
    }
    __builtin_amdgcn_s_setprio(0);
  }

  // epilogue: unnormalized partial O (f32, contiguous 4-elem chunks) + (m, l)
  {
    int s = q0 + lr;
    size_t r = ((size_t)z * nbh + bh) * 2048 + s;
#pragma unroll
    for (int d = 0; d < 4; ++d)
      *(f32x4*)(Op + r * 64 + d * 16 + lh * 4) = oacc[d];
    if (lh == 0) { ml[r * 2] = mrow; ml[r * 2 + 1] = lsum; }
  }
}

// combine 2 KV-split partials -> ctx (bf16, [b][s][h*64+d] layout)
__global__ __launch_bounds__(256) void attn_combine(const float* __restrict__ Op,
                                                    const float* __restrict__ ml,
                                                    u16* __restrict__ ctx, int nbh) {
  size_t i = (size_t)blockIdx.x * 256 + threadIdx.x;   // nbh*2048*16 threads
  int d4 = (int)(i & 15);
  size_t rs = i >> 4;
  size_t zs = (size_t)nbh * 2048;
  float m0 = ml[rs * 2],        l0 = ml[rs * 2 + 1];
  float m1 = ml[(zs + rs) * 2], l1 = ml[(zs + rs) * 2 + 1];
  float mx = fmaxf(m0, m1);
  float a0 = exp2f(m0 - mx), a1 = exp2f(m1 - mx);
  float inv = 1.f / (l0 * a0 + l1 * a1);
  a0 *= inv; a1 *= inv;
  f32x4 o0 = *(const f32x4*)(Op + rs * 64 + d4 * 4);
  f32x4 o1 = *(const f32x4*)(Op + (zs + rs) * 64 + d4 * 4);
  int bh = (int)(rs >> 11), s = (int)(rs & 2047);
  int b = bh / 12, h = bh - b * 12;
  u16x4 r;
#pragma unroll
  for (int k = 0; k < 4; ++k) r[k] = f2b(o0[k] * a0 + o1[k] * a1);
  *(u16x4*)(ctx + ((size_t)(b * 2048 + s)) * 768 + h * 64 + d4 * 4) = r;
}

// ---------------------------------------------------------------------------
// residual + LayerNorm over 768; optionally emit bf16 copy for next GEMM
// ---------------------------------------------------------------------------
__global__ __launch_bounds__(256) void resid_ln(const float* __restrict__ xin,
                                                const float* __restrict__ yin,
                                                const float* __restrict__ gamma,
                                                const float* __restrict__ beta,
                                                float* __restrict__ outf,
                                                u16* __restrict__ outb) {
  const int row = blockIdx.x, t = threadIdx.x;
  const size_t base = (size_t)row * 768;
  float v[3], s = 0.f, s2 = 0.f;
#pragma unroll
  for (int k = 0; k < 3; ++k) {
    int c = t + k * 256;
    float val = xin[base + c] + yin[base + c];
    v[k] = val; s += val; s2 += val * val;
  }
#pragma unroll
  for (int off = 32; off > 0; off >>= 1) {
    s += __shfl_down(s, off, 64);
    s2 += __shfl_down(s2, off, 64);
  }
  __shared__ float red[8];
  int lane = t & 63, wave = t >> 6;
  if (lane == 0) { red[wave] = s; red[4 + wave] = s2; }
  __syncthreads();
  s = red[0] + red[1] + red[2] + red[3];
  s2 = red[4] + red[5] + red[6] + red[7];
  const float inv = 1.f / 768.f;
  float mu = s * inv;
  float var = fmaxf(s2 * inv - mu * mu, 0.f);
  float rs = rsqrtf(var + 1e-5f);
#pragma unroll
  for (int k = 0; k < 3; ++k) {
    int c = t + k * 256;
    float o = (v[k] - mu) * rs * gamma[c] + beta[c];
    if (outf) outf[base + c] = o;
    if (outb) outb[base + c] = f2b(o);
  }
}

// ---------------------------------------------------------------------------
extern "C" void kernel_launch(void* const* d_in, const int* in_sizes, int n_in,
                              void* d_out, int out_size, void* d_ws, size_t ws_size,
                              hipStream_t stream) {
  const float* x   = (const float*)d_in[0];
  const float* Wq  = (const float*)d_in[1];
  const float* bq  = (const float*)d_in[2];
  const float* Wk  = (const float*)d_in[3];
  const float* bk  = (const float*)d_in[4];
  const float* Wv  = (const float*)d_in[5];
  const float* bv  = (const float*)d_in[6];
  const float* Wo  = (const float*)d_in[7];
  const float* bo  = (const float*)d_in[8];
  const float* W1  = (const float*)d_in[9];
  const float* b1  = (const float*)d_in[10];
  const float* W2  = (const float*)d_in[11];
  const float* b2  = (const float*)d_in[12];
  const float* g1  = (const float*)d_in[13];
  const float* be1 = (const float*)d_in[14];
  const float* g2  = (const float*)d_in[15];
  const float* be2 = (const float*)d_in[16];
  float* out = (float*)d_out;

  const int M = in_sizes[0] / 768;   // 4096 tokens
  const int B = M / 2048;            // 2
  const int nbh = B * 12;

  char* ws = (char*)d_ws;
  size_t off = 0;
  auto alloc = [&](size_t bytes) -> void* {
    void* p = ws + off;
    off += (bytes + 255) & ~(size_t)255;
    return p;
  };
  u16*   Wqkv_t = (u16*)alloc((size_t)2304 * 768 * 2);
  u16*   Wo_t   = (u16*)alloc((size_t)768 * 768 * 2);
  u16*   W1_t   = (u16*)alloc((size_t)3072 * 768 * 2);
  u16*   W2_t   = (u16*)alloc((size_t)768 * 3072 * 2);
  float* bqkv   = (float*)alloc(2304 * 4);
  u16*   Xb     = (u16*)alloc((size_t)M * 768 * 2);      // reused as ctx
  u16*   Qh     = (u16*)alloc((size_t)M * 768 * 2);
  u16*   Kh     = (u16*)alloc((size_t)M * 768 * 2);
  u16*   Vh     = (u16*)alloc((size_t)M * 768 * 2);
  u16*   Vt     = (u16*)alloc((size_t)M * 768 * 2);
  // shared region: [attn phase] Op (2 x nbh x 2048 x 64 f32) + ml
  //                [later]      proj (M*768 f32) + x1f (M*768 f32)
  size_t opElems = (size_t)2 * nbh * 2048 * 64;
  size_t mlElems = (size_t)2 * nbh * 2048 * 2;
  size_t regionA = (opElems + mlElems) * 4;
  size_t regionB = (size_t)M * 768 * 4 * 2;
  float* region = (float*)alloc(regionA > regionB ? regionA : regionB);
  float* Op   = region;
  float* ml   = region + opElems;
  float* proj = region;                       // alive only after combine
  float* x1f  = region + (size_t)M * 768;
  u16*   x1b  = (u16*)alloc((size_t)M * 768 * 2);
  u16*   hb   = (u16*)alloc((size_t)M * 3072 * 2);
  u16*   ctx  = Xb;
  float* ffn  = proj;

  dim3 tb(32, 8);
  transpose_conv<<<dim3(24, 24), tb, 0, stream>>>(Wq, Wqkv_t, 768, 768);
  transpose_conv<<<dim3(24, 24), tb, 0, stream>>>(Wk, Wqkv_t + (size_t)768 * 768, 768, 768);
  transpose_conv<<<dim3(24, 24), tb, 0, stream>>>(Wv, Wqkv_t + (size_t)1536 * 768, 768, 768);
  transpose_conv<<<dim3(24, 24), tb, 0, stream>>>(Wo, Wo_t, 768, 768);
  transpose_conv<<<dim3(96, 24), tb, 0, stream>>>(W1, W1_t, 768, 3072);
  transpose_conv<<<dim3(24, 96), tb, 0, stream>>>(W2, W2_t, 3072, 768);
  concat_bias<<<9, 256, 0, stream>>>(bq, bk, bv, bqkv);
  conv_bf16<<<(M * 768) / 1024, 256, 0, stream>>>(x, Xb);

  gemm_bt<2><<<dim3(2304 / 128, M / 128), 256, 0, stream>>>(
      Xb, Wqkv_t, bqkv, nullptr, nullptr, Qh, Kh, Vh, M, 2304, 768);

  transpose_v<<<dim3(2, 64, nbh), tb, 0, stream>>>(Vh, Vt);

  attn<<<dim3(16, nbh, 2), 512, 0, stream>>>(Qh, Kh, Vt, Op, ml, nbh, 16);
  attn_combine<<<nbh * 128, 256, 0, stream>>>(Op, ml, ctx, nbh);

  gemm_bt<0><<<dim3(768 / 128, M / 128), 256, 0, stream>>>(
      ctx, Wo_t, bo, proj, nullptr, nullptr, nullptr, nullptr, M, 768, 768);

  resid_ln<<<M, 256, 0, stream>>>(x, proj, g1, be1, x1f, x1b);

  gemm_bt<1><<<dim3(3072 / 128, M / 128), 256, 0, stream>>>(
      x1b, W1_t, b1, nullptr, hb, nullptr, nullptr, nullptr, M, 3072, 768);
  gemm_bt<0><<<dim3(768 / 128, M / 128), 256, 0, stream>>>(
      hb, W2_t, b2, ffn, nullptr, nullptr, nullptr, nullptr, M, 768, 3072);

  resid_ln<<<M, 256, 0, stream>>>(x1f, ffn, g2, be2, out, nullptr);
}

// Round 5
// 231.786 us; speedup vs baseline: 1.5373x; 1.1757x over previous
//
#include <hip/hip_runtime.h>
#include <cstdint>

// ---------------------------------------------------------------------------
// EncoderLayer: x -> MHA(flash, KV-split, swapped-QK^T in-lane softmax)
//               -> +res,LN -> FFN -> +res,LN
// B=2, S=2048, D=768, H=12, Dk=64, Dff=3072. fp32 in/out, bf16 MFMA internal.
// ---------------------------------------------------------------------------

typedef unsigned short u16;
typedef unsigned int u32;
typedef __attribute__((ext_vector_type(4))) float f32x4;
typedef __attribute__((ext_vector_type(8))) short s16x8;   // 8 bf16 = 4 VGPRs
typedef __attribute__((ext_vector_type(4))) u16  u16x4;
typedef __attribute__((ext_vector_type(2))) u32  u32x2;

#define AS1 __attribute__((address_space(1)))
#define AS3 __attribute__((address_space(3)))

__device__ __forceinline__ u16 f2b(float f) {            // fp32 -> bf16 RNE
  union { float f; unsigned u; } v; v.f = f;
  unsigned r = v.u + 0x7FFFu + ((v.u >> 16) & 1u);
  return (u16)(r >> 16);
}

// async global->LDS, 16B per lane; LDS dest is wave-uniform base + lane*16
__device__ __forceinline__ void gl_lds16(const void* g, void* lds_uniform_base) {
  __builtin_amdgcn_global_load_lds((const AS1 void*)g, (AS3 void*)lds_uniform_base, 16, 0, 0);
}

__device__ __forceinline__ f32x4 mfma16(s16x8 a, s16x8 b, f32x4 c) {
  return __builtin_amdgcn_mfma_f32_16x16x32_bf16(a, b, c, 0, 0, 0);
}

__device__ __forceinline__ u32 cvt_pk_bf16(float lo, float hi) {
  u32 r;
  asm("v_cvt_pk_bf16_f32 %0, %1, %2" : "=v"(r) : "v"(lo), "v"(hi));
  return r;
}

// ---------------------------------------------------------------------------
// small conversion kernels (run every call; no caching allowed)
// ---------------------------------------------------------------------------

__global__ __launch_bounds__(256) void transpose_conv(const float* __restrict__ W,
                                                      u16* __restrict__ Wt, int K, int N) {
  __shared__ float tile[32][33];
  int n0 = blockIdx.x * 32, k0 = blockIdx.y * 32;
  int x = threadIdx.x, y = threadIdx.y;            // (32, 8)
#pragma unroll
  for (int yy = 0; yy < 32; yy += 8)
    tile[y + yy][x] = W[(size_t)(k0 + y + yy) * N + n0 + x];
  __syncthreads();
#pragma unroll
  for (int yy = 0; yy < 32; yy += 8)
    Wt[(size_t)(n0 + y + yy) * K + k0 + x] = f2b(tile[x][y + yy]);
}

__global__ __launch_bounds__(256) void transpose_v(const u16* __restrict__ Vh,
                                                   u16* __restrict__ Vt) {
  __shared__ u16 tile[32][33];
  int bh = blockIdx.z;
  int d0 = blockIdx.x * 32, s0 = blockIdx.y * 32;
  const u16* src = Vh + (size_t)bh * 2048 * 64;
  u16* dst = Vt + (size_t)bh * 64 * 2048;
  int x = threadIdx.x, y = threadIdx.y;
#pragma unroll
  for (int yy = 0; yy < 32; yy += 8)
    tile[y + yy][x] = src[(size_t)(s0 + y + yy) * 64 + d0 + x];
  __syncthreads();
#pragma unroll
  for (int yy = 0; yy < 32; yy += 8)
    dst[(size_t)(d0 + y + yy) * 2048 + s0 + x] = tile[x][y + yy];
}

__global__ __launch_bounds__(256) void conv_bf16(const float* __restrict__ in,
                                                 u16* __restrict__ out) {
  size_t i = ((size_t)blockIdx.x * 256 + threadIdx.x) * 4;
  f32x4 v = *(const f32x4*)(in + i);
  u16x4 o;
#pragma unroll
  for (int k = 0; k < 4; ++k) o[k] = f2b(v[k]);
  *(u16x4*)(out + i) = o;
}

__global__ void concat_bias(const float* __restrict__ bq, const float* __restrict__ bk,
                            const float* __restrict__ bv, float* __restrict__ o) {
  int i = blockIdx.x * 256 + threadIdx.x;          // 9 blocks * 256 = 2304
  o[i] = (i < 768) ? bq[i] : (i < 1536) ? bk[i - 768] : bv[i - 1536];
}

// ---------------------------------------------------------------------------
// GEMM: C(M,N) = A(M,K)[bf16 rowmajor] * Bt(N,K)^T[bf16] + bias, fused epilogue
// m97 structure + both-sides XOR LDS swizzle (T2) + split-K via blockIdx.z.
// MODE 0: fp32 out (partial per z-chunk; bias only in chunk 0)
// MODE 1: relu -> bf16 out (no split)
// MODE 2: QKV head-split; Q pre-scaled by 0.125*log2(e) (log2-domain softmax)
// ---------------------------------------------------------------------------
template <int MODE>
__global__ __launch_bounds__(256) void gemm_bt(const u16* __restrict__ A,
                                               const u16* __restrict__ Bt,
                                               const float* __restrict__ bias,
                                               float* __restrict__ Cf, u16* __restrict__ Cb,
                                               u16* __restrict__ Qo, u16* __restrict__ Ko,
                                               u16* __restrict__ Vo, int M, int N, int K,
                                               int Klen) {
  __shared__ __align__(16) u16 lsA[128 * 64];
  __shared__ __align__(16) u16 lsB[128 * 64];
  const int tid = threadIdx.x;
  const int lane = tid & 63, wave = tid >> 6;
  const int lr = lane & 15, lh = lane >> 4;
  const int wr = wave >> 1, wc = wave & 1;
  const int m0 = blockIdx.y * 128;
  const int n0 = blockIdx.x * 128;
  const int kB = blockIdx.z * Klen;

  f32x4 acc[4][4];
#pragma unroll
  for (int i = 0; i < 4; ++i)
#pragma unroll
    for (int j = 0; j < 4; ++j) acc[i][j] = f32x4{0.f, 0.f, 0.f, 0.f};

  const size_t aBase = (size_t)m0 * K;
  const size_t bBase = (size_t)n0 * K;
  // staging geometry (pre-swizzled source, linear LDS dest; rule #21)
  const int srow8 = tid >> 3;                      // row within 32-row group
  const int scolb = ((tid & 7) * 16) ^ ((srow8 & 7) << 4);
  const int xk = (lr & 7) << 4;                    // ds_read XOR key

  for (int kt = kB; kt < kB + Klen; kt += 64) {
#pragma unroll
    for (int i = 0; i < 4; ++i) {
      int row = i * 32 + srow8;
      int ldsOff = i * 4096 + wave * 1024;
      gl_lds16(A + aBase + (size_t)row * K + kt + (scolb >> 1), (char*)lsA + ldsOff);
      gl_lds16(Bt + bBase + (size_t)row * K + kt + (scolb >> 1), (char*)lsB + ldsOff);
    }
    __syncthreads();
    const char* baA = (const char*)lsA;
    const char* baB = (const char*)lsB;
#pragma unroll
    for (int ks = 0; ks < 2; ++ks) {
      int cb = (ks * 64 + lh * 16) ^ xk;
      s16x8 a[4], b[4];
#pragma unroll
      for (int i = 0; i < 4; ++i) {
        a[i] = *(const s16x8*)(baA + (wr * 64 + i * 16 + lr) * 128 + cb);
        b[i] = *(const s16x8*)(baB + (wc * 64 + i * 16 + lr) * 128 + cb);
      }
#pragma unroll
      for (int i = 0; i < 4; ++i)
#pragma unroll
        for (int j = 0; j < 4; ++j) acc[i][j] = mfma16(a[i], b[j], acc[i][j]);
    }
    __syncthreads();
  }

  float* CfP = Cf + (size_t)blockIdx.z * M * N;    // partial slot (MODE 0)
#pragma unroll
  for (int i = 0; i < 4; ++i) {
    int growb = m0 + wr * 64 + i * 16 + lh * 4;
#pragma unroll
    for (int j = 0; j < 4; ++j) {
      int col = n0 + wc * 64 + j * 16 + lr;
      float bv = (MODE != 0 || blockIdx.z == 0) ? bias[col] : 0.f;
#pragma unroll
      for (int q = 0; q < 4; ++q) {
        int grow = growb + q;
        float v = acc[i][j][q] + bv;
        if (MODE == 0) {
          CfP[(size_t)grow * N + col] = v;
        } else if (MODE == 1) {
          Cb[(size_t)grow * N + col] = f2b(fmaxf(v, 0.f));
        } else {
          int sel = col / 768;
          int c2 = col - sel * 768;
          int h = c2 >> 6, d = c2 & 63;
          int b = grow >> 11, s = grow & 2047;
          size_t idx = (((size_t)(b * 12 + h)) * 2048 + s) * 64 + d;
          // Q scale: (1/sqrt(64)) * log2(e) -> log2-domain softmax
          float vv = (sel == 0) ? v * 0.1803368801f : v;
          u16* dst = (sel == 0) ? Qo : (sel == 1) ? Ko : Vo;
          dst[idx] = f2b(vv);
        }
      }
    }
  }
}

// ---------------------------------------------------------------------------
// Flash attention v4: KV split-K, SWAPPED-operand MFMA. (frozen this round)
// ---------------------------------------------------------------------------
__global__ __launch_bounds__(512) void attn(const u16* __restrict__ Qh,
                                            const u16* __restrict__ Kh,
                                            const u16* __restrict__ Vt,
                                            float* __restrict__ Op,
                                            float* __restrict__ ml,
                                            int nbh, int ntile) {
  __shared__ __align__(16) u16 lsK[2][64 * 64];   // [buf][key][dim]   swizzled
  __shared__ __align__(16) u16 lsV[2][64 * 64];   // [buf][dim][key]   swizzled
  __shared__ __align__(16) u16 lsP[8][16 * 64];   // per-wave [qrow][key] swizzled
  const int tid = threadIdx.x, lane = tid & 63, wave = tid >> 6;
  const int lr = lane & 15, lh = lane >> 4;

  int bx = blockIdx.x, bh = blockIdx.y, z = blockIdx.z;
  {
    int total = 16 * nbh * 2;
    if ((total & 7) == 0) {
      int lin = bx + 16 * (bh + nbh * z);
      int nl = (lin & 7) * (total >> 3) + (lin >> 3);
      bx = nl & 15;
      bh = (nl >> 4) % nbh;
      z = nl / (16 * nbh);
    }
  }
  const int q0 = bx * 128 + wave * 16;
  const size_t kvBase = (size_t)bh * 2048 * 64;
  const int tB = z * ntile;

  const int srow = tid >> 3;                       // 0..63
  const int scol = (((tid & 7) * 16) ^ ((srow & 7) << 4)) >> 1;  // elem offset
  const u16* kSrcBase = Kh + kvBase + (size_t)srow * 64 + scol;
  const u16* vSrcBase = Vt + kvBase + (size_t)srow * 2048 + scol;

  s16x8 qf[2];
#pragma unroll
  for (int ks = 0; ks < 2; ++ks)
    qf[ks] = *(const s16x8*)(Qh + kvBase + (size_t)(q0 + lr) * 64 + ks * 32 + lh * 8);

  f32x4 oacc[4];
  float mrow = -1e30f, lsum = 0.f;
#pragma unroll
  for (int d = 0; d < 4; ++d) oacc[d] = f32x4{0.f, 0.f, 0.f, 0.f};

  gl_lds16(kSrcBase + (size_t)tB * 4096, (char*)lsK[0] + wave * 1024);
  gl_lds16(vSrcBase + tB * 64,           (char*)lsV[0] + wave * 1024);

  for (int it = 0; it < ntile; ++it) {
    const int cur = it & 1;
    __syncthreads();

    s16x8 kb[2][4];
#pragma unroll
    for (int ks = 0; ks < 2; ++ks)
#pragma unroll
      for (int j = 0; j < 4; ++j) {
        int r = j * 16 + lr;
        kb[ks][j] = *(const s16x8*)((const char*)lsK[cur] + r * 128 +
                                    ((ks * 64 + lh * 16) ^ ((r & 7) << 4)));
      }

    if (it + 1 < ntile) {
      int t = tB + it + 1;
      gl_lds16(kSrcBase + (size_t)t * 4096, (char*)lsK[cur ^ 1] + wave * 1024);
      gl_lds16(vSrcBase + t * 64,           (char*)lsV[cur ^ 1] + wave * 1024);
    }

    f32x4 st[4];
#pragma unroll
    for (int j = 0; j < 4; ++j) st[j] = f32x4{0.f, 0.f, 0.f, 0.f};
    __builtin_amdgcn_s_setprio(1);
#pragma unroll
    for (int ks = 0; ks < 2; ++ks)
#pragma unroll
      for (int j = 0; j < 4; ++j) st[j] = mfma16(kb[ks][j], qf[ks], st[j]);
    __builtin_amdgcn_s_setprio(0);

    float mx;
    {
      float a0 = fmaxf(fmaxf(st[0][0], st[0][1]), fmaxf(st[0][2], st[0][3]));
      float a1 = fmaxf(fmaxf(st[1][0], st[1][1]), fmaxf(st[1][2], st[1][3]));
      float a2 = fmaxf(fmaxf(st[2][0], st[2][1]), fmaxf(st[2][2], st[2][3]));
      float a3 = fmaxf(fmaxf(st[3][0], st[3][1]), fmaxf(st[3][2], st[3][3]));
      mx = fmaxf(fmaxf(a0, a1), fmaxf(a2, a3));
      mx = fmaxf(mx, __shfl_xor(mx, 16));
      mx = fmaxf(mx, __shfl_xor(mx, 32));
    }
    if (__any(mx > mrow + 11.f)) {
      float mn = fmaxf(mrow, mx);
      float al = exp2f(mrow - mn);
      mrow = mn;
      lsum *= al;
#pragma unroll
      for (int d = 0; d < 4; ++d)
#pragma unroll
        for (int q = 0; q < 4; ++q) oacc[d][q] *= al;
    }

    float ps = 0.f;
#pragma unroll
    for (int j = 0; j < 4; ++j) {
      float p0 = exp2f(st[j][0] - mrow);
      float p1 = exp2f(st[j][1] - mrow);
      float p2 = exp2f(st[j][2] - mrow);
      float p3 = exp2f(st[j][3] - mrow);
      ps += (p0 + p1) + (p2 + p3);
      u32x2 pk;
      pk.x = cvt_pk_bf16(p0, p1);
      pk.y = cvt_pk_bf16(p2, p3);
      *(u32x2*)((char*)lsP[wave] + lr * 128 + ((j * 32 + lh * 8) ^ ((lr & 7) << 4))) = pk;
    }
    ps += __shfl_xor(ps, 16);
    ps += __shfl_xor(ps, 32);
    lsum += ps;

    __builtin_amdgcn_s_setprio(1);
#pragma unroll
    for (int ks = 0; ks < 2; ++ks) {
      s16x8 pa = *(const s16x8*)((const char*)lsP[wave] + lr * 128 +
                                 ((ks * 64 + lh * 16) ^ ((lr & 7) << 4)));
#pragma unroll
      for (int d = 0; d < 4; ++d) {
        int r = d * 16 + lr;
        s16x8 vb = *(const s16x8*)((const char*)lsV[cur] + r * 128 +
                                   ((ks * 64 + lh * 16) ^ ((r & 7) << 4)));
        oacc[d] = mfma16(vb, pa, oacc[d]);
      }
    }
    __builtin_amdgcn_s_setprio(0);
  }

  {
    int s = q0 + lr;
    size_t r = ((size_t)z * nbh + bh) * 2048 + s;
#pragma unroll
    for (int d = 0; d < 4; ++d)
      *(f32x4*)(Op + r * 64 + d * 16 + lh * 4) = oacc[d];
    if (lh == 0) { ml[r * 2] = mrow; ml[r * 2 + 1] = lsum; }
  }
}

// combine 2 KV-split partials -> ctx (bf16, [b][s][h*64+d] layout)
__global__ __launch_bounds__(256) void attn_combine(const float* __restrict__ Op,
                                                    const float* __restrict__ ml,
                                                    u16* __restrict__ ctx, int nbh) {
  size_t i = (size_t)blockIdx.x * 256 + threadIdx.x;   // nbh*2048*16 threads
  int d4 = (int)(i & 15);
  size_t rs = i >> 4;
  size_t zs = (size_t)nbh * 2048;
  float m0 = ml[rs * 2],        l0 = ml[rs * 2 + 1];
  float m1 = ml[(zs + rs) * 2], l1 = ml[(zs + rs) * 2 + 1];
  float mx = fmaxf(m0, m1);
  float a0 = exp2f(m0 - mx), a1 = exp2f(m1 - mx);
  float inv = 1.f / (l0 * a0 + l1 * a1);
  a0 *= inv; a1 *= inv;
  f32x4 o0 = *(const f32x4*)(Op + rs * 64 + d4 * 4);
  f32x4 o1 = *(const f32x4*)(Op + (zs + rs) * 64 + d4 * 4);
  int bh = (int)(rs >> 11), s = (int)(rs & 2047);
  int b = bh / 12, h = bh - b * 12;
  u16x4 r;
#pragma unroll
  for (int k = 0; k < 4; ++k) r[k] = f2b(o0[k] * a0 + o1[k] * a1);
  *(u16x4*)(ctx + ((size_t)(b * 2048 + s)) * 768 + h * 64 + d4 * 4) = r;
}

// ---------------------------------------------------------------------------
// residual + LayerNorm over 768; yin = sum of NP partials (split-K GEMM out);
// optionally emit bf16 copy for next GEMM
// ---------------------------------------------------------------------------
template <int NP>
__global__ __launch_bounds__(256) void resid_ln(const float* __restrict__ xin,
                                                const float* __restrict__ yp,
                                                size_t pstride,
                                                const float* __restrict__ gamma,
                                                const float* __restrict__ beta,
                                                float* __restrict__ outf,
                                                u16* __restrict__ outb) {
  const int row = blockIdx.x, t = threadIdx.x;
  const size_t base = (size_t)row * 768;
  float v[3], s = 0.f, s2 = 0.f;
#pragma unroll
  for (int k = 0; k < 3; ++k) {
    int c = t + k * 256;
    float val = xin[base + c];
#pragma unroll
    for (int p = 0; p < NP; ++p) val += yp[p * pstride + base + c];
    v[k] = val; s += val; s2 += val * val;
  }
#pragma unroll
  for (int off = 32; off > 0; off >>= 1) {
    s += __shfl_down(s, off, 64);
    s2 += __shfl_down(s2, off, 64);
  }
  __shared__ float red[8];
  int lane = t & 63, wave = t >> 6;
  if (lane == 0) { red[wave] = s; red[4 + wave] = s2; }
  __syncthreads();
  s = red[0] + red[1] + red[2] + red[3];
  s2 = red[4] + red[5] + red[6] + red[7];
  const float inv = 1.f / 768.f;
  float mu = s * inv;
  float var = fmaxf(s2 * inv - mu * mu, 0.f);
  float rs = rsqrtf(var + 1e-5f);
#pragma unroll
  for (int k = 0; k < 3; ++k) {
    int c = t + k * 256;
    float o = (v[k] - mu) * rs * gamma[c] + beta[c];
    if (outf) outf[base + c] = o;
    if (outb) outb[base + c] = f2b(o);
  }
}

// ---------------------------------------------------------------------------
extern "C" void kernel_launch(void* const* d_in, const int* in_sizes, int n_in,
                              void* d_out, int out_size, void* d_ws, size_t ws_size,
                              hipStream_t stream) {
  const float* x   = (const float*)d_in[0];
  const float* Wq  = (const float*)d_in[1];
  const float* bq  = (const float*)d_in[2];
  const float* Wk  = (const float*)d_in[3];
  const float* bk  = (const float*)d_in[4];
  const float* Wv  = (const float*)d_in[5];
  const float* bv  = (const float*)d_in[6];
  const float* Wo  = (const float*)d_in[7];
  const float* bo  = (const float*)d_in[8];
  const float* W1  = (const float*)d_in[9];
  const float* b1  = (const float*)d_in[10];
  const float* W2  = (const float*)d_in[11];
  const float* b2  = (const float*)d_in[12];
  const float* g1  = (const float*)d_in[13];
  const float* be1 = (const float*)d_in[14];
  const float* g2  = (const float*)d_in[15];
  const float* be2 = (const float*)d_in[16];
  float* out = (float*)d_out;

  const int M = in_sizes[0] / 768;   // 4096 tokens
  const int B = M / 2048;            // 2
  const int nbh = B * 12;

  char* ws = (char*)d_ws;
  size_t off = 0;
  auto alloc = [&](size_t bytes) -> void* {
    void* p = ws + off;
    off += (bytes + 255) & ~(size_t)255;
    return p;
  };
  u16*   Wqkv_t = (u16*)alloc((size_t)2304 * 768 * 2);
  u16*   Wo_t   = (u16*)alloc((size_t)768 * 768 * 2);
  u16*   W1_t   = (u16*)alloc((size_t)3072 * 768 * 2);
  u16*   W2_t   = (u16*)alloc((size_t)768 * 3072 * 2);
  float* bqkv   = (float*)alloc(2304 * 4);
  u16*   Xb     = (u16*)alloc((size_t)M * 768 * 2);      // reused as ctx
  u16*   Qh     = (u16*)alloc((size_t)M * 768 * 2);      // later: proj partials
  u16*   Kh     = (u16*)alloc((size_t)M * 768 * 2);
  u16*   Vh     = (u16*)alloc((size_t)M * 768 * 2);
  u16*   Vt     = (u16*)alloc((size_t)M * 768 * 2);

  // attn scratch / FFN2 partials share one region
  size_t opElems = (size_t)2 * nbh * 2048 * 64;
  size_t mlElems = (size_t)2 * nbh * 2048 * 2;
  size_t attnBytes = (opElems + mlElems) * 4;
  size_t pstride = (size_t)M * 768;                      // elems per partial
  // decide FFN2 split by available workspace
  size_t fixedRest = pstride * 4 /*x1f*/ + pstride * 2 /*x1b*/ +
                     (size_t)M * 3072 * 2 /*hb*/ + 4096 /*padding slack*/;
  size_t need4 = off + ((pstride * 4 * 4 > attnBytes ? pstride * 4 * 4 : attnBytes)) + fixedRest;
  const int SPLIT2 = (ws_size >= need4) ? 4 : 2;
  size_t regionBytes = pstride * 4 * SPLIT2;
  if (regionBytes < attnBytes) regionBytes = attnBytes;
  float* region = (float*)alloc(regionBytes);
  float* Op   = region;
  float* ml   = region + opElems;
  float* ffnPart  = region;                    // alive after attn_combine
  float* projPart = (float*)Qh;                // alive after attn (2 partials)
  float* x1f  = (float*)alloc(pstride * 4);
  u16*   x1b  = (u16*)alloc(pstride * 2);
  u16*   hb   = (u16*)alloc((size_t)M * 3072 * 2);
  u16*   ctx  = Xb;

  dim3 tb(32, 8);
  transpose_conv<<<dim3(24, 24), tb, 0, stream>>>(Wq, Wqkv_t, 768, 768);
  transpose_conv<<<dim3(24, 24), tb, 0, stream>>>(Wk, Wqkv_t + (size_t)768 * 768, 768, 768);
  transpose_conv<<<dim3(24, 24), tb, 0, stream>>>(Wv, Wqkv_t + (size_t)1536 * 768, 768, 768);
  transpose_conv<<<dim3(24, 24), tb, 0, stream>>>(Wo, Wo_t, 768, 768);
  transpose_conv<<<dim3(96, 24), tb, 0, stream>>>(W1, W1_t, 768, 3072);
  transpose_conv<<<dim3(24, 96), tb, 0, stream>>>(W2, W2_t, 3072, 768);
  concat_bias<<<9, 256, 0, stream>>>(bq, bk, bv, bqkv);
  conv_bf16<<<(M * 768) / 1024, 256, 0, stream>>>(x, Xb);

  gemm_bt<2><<<dim3(2304 / 128, M / 128), 256, 0, stream>>>(
      Xb, Wqkv_t, bqkv, nullptr, nullptr, Qh, Kh, Vh, M, 2304, 768, 768);

  transpose_v<<<dim3(2, 64, nbh), tb, 0, stream>>>(Vh, Vt);

  attn<<<dim3(16, nbh, 2), 512, 0, stream>>>(Qh, Kh, Vt, Op, ml, nbh, 16);
  attn_combine<<<nbh * 128, 256, 0, stream>>>(Op, ml, ctx, nbh);

  // output projection, split-K x2 -> partials over Qh..Vt region
  gemm_bt<0><<<dim3(768 / 128, M / 128, 2), 256, 0, stream>>>(
      ctx, Wo_t, bo, projPart, nullptr, nullptr, nullptr, nullptr, M, 768, 768, 384);

  resid_ln<2><<<M, 256, 0, stream>>>(x, projPart, pstride, g1, be1, x1f, x1b);

  gemm_bt<1><<<dim3(3072 / 128, M / 128), 256, 0, stream>>>(
      x1b, W1_t, b1, nullptr, hb, nullptr, nullptr, nullptr, M, 3072, 768, 768);

  // FFN2, split-K x4 (or x2 if ws tight) -> partials in region
  if (SPLIT2 == 4) {
    gemm_bt<0><<<dim3(768 / 128, M / 128, 4), 256, 0, stream>>>(
        hb, W2_t, b2, ffnPart, nullptr, nullptr, nullptr, nullptr, M, 768, 3072, 768);
    resid_ln<4><<<M, 256, 0, stream>>>(x1f, ffnPart, pstride, g2, be2, out, nullptr);
  } else {
    gemm_bt<0><<<dim3(768 / 128, M / 128, 2), 256, 0, stream>>>(
        hb, W2_t, b2, ffnPart, nullptr, nullptr, nullptr, nullptr, M, 768, 3072, 1536);
    resid_ln<2><<<M, 256, 0, stream>>>(x1f, ffnPart, pstride, g2, be2, out, nullptr);
  }
}

// Round 6
// 218.803 us; speedup vs baseline: 1.6285x; 1.0593x over previous
//
#include <hip/hip_runtime.h>
#include <cstdint>

// ---------------------------------------------------------------------------
// EncoderLayer: x -> MHA(flash, KV-split, swapped-QK^T in-lane softmax)
//               -> +res,LN -> FFN -> +res,LN
// B=2, S=2048, D=768, H=12, Dk=64, Dff=3072. fp32 in/out, bf16 MFMA internal.
// ---------------------------------------------------------------------------

typedef unsigned short u16;
typedef unsigned int u32;
typedef __attribute__((ext_vector_type(4))) float f32x4;
typedef __attribute__((ext_vector_type(8))) short s16x8;   // 8 bf16 = 4 VGPRs
typedef __attribute__((ext_vector_type(4))) u16  u16x4;
typedef __attribute__((ext_vector_type(2))) u32  u32x2;

#define AS1 __attribute__((address_space(1)))
#define AS3 __attribute__((address_space(3)))

__device__ __forceinline__ u16 f2b(float f) {            // fp32 -> bf16 RNE
  union { float f; unsigned u; } v; v.f = f;
  unsigned r = v.u + 0x7FFFu + ((v.u >> 16) & 1u);
  return (u16)(r >> 16);
}

// async global->LDS, 16B per lane; LDS dest is wave-uniform base + lane*16
__device__ __forceinline__ void gl_lds16(const void* g, void* lds_uniform_base) {
  __builtin_amdgcn_global_load_lds((const AS1 void*)g, (AS3 void*)lds_uniform_base, 16, 0, 0);
}

__device__ __forceinline__ f32x4 mfma16(s16x8 a, s16x8 b, f32x4 c) {
  return __builtin_amdgcn_mfma_f32_16x16x32_bf16(a, b, c, 0, 0, 0);
}

__device__ __forceinline__ u32 cvt_pk_bf16(float lo, float hi) {
  u32 r;
  asm("v_cvt_pk_bf16_f32 %0, %1, %2" : "=v"(r) : "v"(lo), "v"(hi));
  return r;
}

// ---------------------------------------------------------------------------
// prep: ALL weight transposes (fp32->bf16^T) + x->bf16 + bias concat in ONE
// launch. Branch is uniform per block (blockIdx range switch).
// blocks: [0,2304)   four 768x768 transposes (Wq,Wk,Wv -> Wqkv_t; Wo -> Wo_t)
//         [2304,4608) W1 (768x3072)
//         [4608,6912) W2 (3072x768)
//         [6912,6912+convBlocks) x -> bf16
//         last 9      bias concat
// ---------------------------------------------------------------------------
__global__ __launch_bounds__(256) void prep(
    const float* __restrict__ Wq, const float* __restrict__ Wk,
    const float* __restrict__ Wv, const float* __restrict__ Wo,
    const float* __restrict__ W1, const float* __restrict__ W2,
    const float* __restrict__ bq, const float* __restrict__ bk,
    const float* __restrict__ bv, const float* __restrict__ x,
    u16* __restrict__ Wqkv_t, u16* __restrict__ Wo_t,
    u16* __restrict__ W1_t, u16* __restrict__ W2_t,
    float* __restrict__ bqkv, u16* __restrict__ Xb, int convBlocks) {
  __shared__ float ts[32][33];
  const int bid = blockIdx.x;
  const int tx = threadIdx.x, ty = threadIdx.y;    // (32, 8)
  if (bid < 6912) {
    const float* W; u16* Wt; int K, N, tile;
    if (bid < 2304) {
      int w = bid / 576; tile = bid - w * 576; K = 768; N = 768;
      W = (w == 0) ? Wq : (w == 1) ? Wk : (w == 2) ? Wv : Wo;
      Wt = (w < 3) ? Wqkv_t + (size_t)w * 768 * 768 : Wo_t;
    } else if (bid < 4608) {
      tile = bid - 2304; K = 768; N = 3072; W = W1; Wt = W1_t;
    } else {
      tile = bid - 4608; K = 3072; N = 768; W = W2; Wt = W2_t;
    }
    int ntx = N >> 5;
    int n0 = (tile % ntx) * 32, k0 = (tile / ntx) * 32;
#pragma unroll
    for (int yy = 0; yy < 32; yy += 8)
      ts[ty + yy][tx] = W[(size_t)(k0 + ty + yy) * N + n0 + tx];
    __syncthreads();
#pragma unroll
    for (int yy = 0; yy < 32; yy += 8)
      Wt[(size_t)(n0 + ty + yy) * K + k0 + tx] = f2b(ts[tx][ty + yy]);
  } else if (bid < 6912 + convBlocks) {
    int t = ty * 32 + tx;
    size_t i = ((size_t)(bid - 6912) * 256 + t) * 4;
    f32x4 v = *(const f32x4*)(x + i);
    u16x4 o;
#pragma unroll
    for (int k = 0; k < 4; ++k) o[k] = f2b(v[k]);
    *(u16x4*)(Xb + i) = o;
  } else {
    int t = ty * 32 + tx;
    int i = (bid - 6912 - convBlocks) * 256 + t;
    if (i < 2304) bqkv[i] = (i < 768) ? bq[i] : (i < 1536) ? bk[i - 768] : bv[i - 1536];
  }
}

// bf16 (S,64) per-head -> bf16 (64,S) per-head (V^T for PV B-operand)
__global__ __launch_bounds__(256) void transpose_v(const u16* __restrict__ Vh,
                                                   u16* __restrict__ Vt) {
  __shared__ u16 tile[32][33];
  int bh = blockIdx.z;
  int d0 = blockIdx.x * 32, s0 = blockIdx.y * 32;
  const u16* src = Vh + (size_t)bh * 2048 * 64;
  u16* dst = Vt + (size_t)bh * 64 * 2048;
  int x = threadIdx.x, y = threadIdx.y;
#pragma unroll
  for (int yy = 0; yy < 32; yy += 8)
    tile[y + yy][x] = src[(size_t)(s0 + y + yy) * 64 + d0 + x];
  __syncthreads();
#pragma unroll
  for (int yy = 0; yy < 32; yy += 8)
    dst[(size_t)(d0 + y + yy) * 2048 + s0 + x] = tile[x][y + yy];
}

// ---------------------------------------------------------------------------
// GEMM: C(M,N) = A(M,K)[bf16 rowmajor] * Bt(N,K)^T[bf16] + bias, fused epilogue
// m97 structure + T2 both-sides swizzle + DOUBLE-BUFFERED LDS with
// stage-before-compute (T3 minimum 2-phase: one barrier per K-step, prefetch
// latency hidden under frag-reads + MFMA) + split-K via blockIdx.z.
// MODE 0: fp32 out (partial per z-chunk; bias only in chunk 0)
// MODE 1: relu -> bf16 out
// MODE 2: QKV head-split; Q pre-scaled by 0.125*log2(e) (log2-domain softmax)
// ---------------------------------------------------------------------------
template <int MODE>
__global__ __launch_bounds__(256) void gemm_bt(const u16* __restrict__ A,
                                               const u16* __restrict__ Bt,
                                               const float* __restrict__ bias,
                                               float* __restrict__ Cf, u16* __restrict__ Cb,
                                               u16* __restrict__ Qo, u16* __restrict__ Ko,
                                               u16* __restrict__ Vo, int M, int N, int K,
                                               int Klen) {
  __shared__ __align__(16) u16 lsA[2][128 * 64];
  __shared__ __align__(16) u16 lsB[2][128 * 64];
  const int tid = threadIdx.x;
  const int lane = tid & 63, wave = tid >> 6;
  const int lr = lane & 15, lh = lane >> 4;
  const int wr = wave >> 1, wc = wave & 1;
  const int m0 = blockIdx.y * 128;
  const int n0 = blockIdx.x * 128;
  const int kB = blockIdx.z * Klen;

  f32x4 acc[4][4];
#pragma unroll
  for (int i = 0; i < 4; ++i)
#pragma unroll
    for (int j = 0; j < 4; ++j) acc[i][j] = f32x4{0.f, 0.f, 0.f, 0.f};

  const size_t aBase = (size_t)m0 * K;
  const size_t bBase = (size_t)n0 * K;
  const int srow8 = tid >> 3;                      // 0..31
  const int scolE = (((tid & 7) * 16) ^ ((srow8 & 7) << 4)) >> 1;
  const int xk = (lr & 7) << 4;                    // ds_read XOR key

  auto stage = [&](int buf, int kt) {
#pragma unroll
    for (int i = 0; i < 4; ++i) {
      int row = i * 32 + srow8;
      int ldsOff = buf * 16384 + i * 4096 + wave * 1024;
      gl_lds16(A + aBase + (size_t)row * K + kt + scolE, (char*)lsA + ldsOff);
      gl_lds16(Bt + bBase + (size_t)row * K + kt + scolE, (char*)lsB + ldsOff);
    }
  };

  const int nk = Klen >> 6;
  stage(0, kB);
  for (int t = 0; t < nk; ++t) {
    const int cur = t & 1;
    __syncthreads();                               // staged[cur] landed
    if (t + 1 < nk) stage(cur ^ 1, kB + (t + 1) * 64);
    const char* baA = (const char*)lsA + cur * 16384;
    const char* baB = (const char*)lsB + cur * 16384;
#pragma unroll
    for (int ks = 0; ks < 2; ++ks) {
      int cb = (ks * 64 + lh * 16) ^ xk;
      s16x8 a[4], b[4];
#pragma unroll
      for (int i = 0; i < 4; ++i) {
        a[i] = *(const s16x8*)(baA + (wr * 64 + i * 16 + lr) * 128 + cb);
        b[i] = *(const s16x8*)(baB + (wc * 64 + i * 16 + lr) * 128 + cb);
      }
#pragma unroll
      for (int i = 0; i < 4; ++i)
#pragma unroll
        for (int j = 0; j < 4; ++j) acc[i][j] = mfma16(a[i], b[j], acc[i][j]);
    }
  }

  float* CfP = Cf + (size_t)blockIdx.z * M * N;    // partial slot (MODE 0)
#pragma unroll
  for (int i = 0; i < 4; ++i) {
    int growb = m0 + wr * 64 + i * 16 + lh * 4;
#pragma unroll
    for (int j = 0; j < 4; ++j) {
      int col = n0 + wc * 64 + j * 16 + lr;
      float bv = (MODE != 0 || blockIdx.z == 0) ? bias[col] : 0.f;
#pragma unroll
      for (int q = 0; q < 4; ++q) {
        int grow = growb + q;
        float v = acc[i][j][q] + bv;
        if (MODE == 0) {
          CfP[(size_t)grow * N + col] = v;
        } else if (MODE == 1) {
          Cb[(size_t)grow * N + col] = f2b(fmaxf(v, 0.f));
        } else {
          int sel = col / 768;
          int c2 = col - sel * 768;
          int h = c2 >> 6, d = c2 & 63;
          int b = grow >> 11, s = grow & 2047;
          size_t idx = (((size_t)(b * 12 + h)) * 2048 + s) * 64 + d;
          float vv = (sel == 0) ? v * 0.1803368801f : v;
          u16* dst = (sel == 0) ? Qo : (sel == 1) ? Ko : Vo;
          dst[idx] = f2b(vv);
        }
      }
    }
  }
}

// ---------------------------------------------------------------------------
// Flash attention v5: KV split-K, swapped-operand MFMA, 4 waves x 32 Q-rows
// (K/V fragment reads amortized over 2 output units; vb shared across units).
// Grid (S/128, B*H, 2), 256 threads. Double-buffered swizzled K/V LDS,
// one barrier per tile, defer-max, XCD-chunked remap.
// ---------------------------------------------------------------------------
__global__ __launch_bounds__(256, 3) void attn(const u16* __restrict__ Qh,
                                               const u16* __restrict__ Kh,
                                               const u16* __restrict__ Vt,
                                               float* __restrict__ Op,
                                               float* __restrict__ ml,
                                               int nbh, int ntile) {
  __shared__ __align__(16) u16 lsK[2][64 * 64];   // [buf][key][dim]   swizzled
  __shared__ __align__(16) u16 lsV[2][64 * 64];   // [buf][dim][key]   swizzled
  __shared__ __align__(16) u16 lsP[4][32 * 64];   // per-wave [qrow][key] swizzled
  const int tid = threadIdx.x, lane = tid & 63, wave = tid >> 6;
  const int lr = lane & 15, lh = lane >> 4;

  int bx = blockIdx.x, bh = blockIdx.y, z = blockIdx.z;
  {
    int total = 16 * nbh * 2;
    if ((total & 7) == 0) {
      int lin = bx + 16 * (bh + nbh * z);
      int nl = (lin & 7) * (total >> 3) + (lin >> 3);
      bx = nl & 15;
      bh = (nl >> 4) % nbh;
      z = nl / (16 * nbh);
    }
  }
  const int q0 = bx * 128 + wave * 32;
  const size_t kvBase = (size_t)bh * 2048 * 64;
  const int tB = z * ntile;

  const int srow = tid >> 3;                       // 0..31
  const int scolE = (((tid & 7) * 16) ^ ((srow & 7) << 4)) >> 1;
  const u16* kSrc = Kh + kvBase + (size_t)srow * 64 + scolE;
  const u16* vSrc = Vt + kvBase + (size_t)srow * 2048 + scolE;

  s16x8 qf[2][2];
#pragma unroll
  for (int i = 0; i < 2; ++i)
#pragma unroll
    for (int ks = 0; ks < 2; ++ks)
      qf[i][ks] = *(const s16x8*)(Qh + kvBase + (size_t)(q0 + i * 16 + lr) * 64 +
                                  ks * 32 + lh * 8);

  f32x4 oacc[2][4];
  float mrow[2], lsum[2];
#pragma unroll
  for (int i = 0; i < 2; ++i) {
    mrow[i] = -1e30f; lsum[i] = 0.f;
#pragma unroll
    for (int d = 0; d < 4; ++d) oacc[i][d] = f32x4{0.f, 0.f, 0.f, 0.f};
  }

  auto stageKV = [&](int buf, int t) {
#pragma unroll
    for (int ii = 0; ii < 2; ++ii) {
      int ldsOff = ii * 4096 + wave * 1024;
      gl_lds16(kSrc + (size_t)(t * 64 + ii * 32) * 64, (char*)lsK[buf] + ldsOff);
      gl_lds16(vSrc + (size_t)ii * 32 * 2048 + t * 64, (char*)lsV[buf] + ldsOff);
    }
  };

  stageKV(0, tB);
  for (int it = 0; it < ntile; ++it) {
    const int cur = it & 1;
    __syncthreads();

    s16x8 kb[2][4];
#pragma unroll
    for (int ks = 0; ks < 2; ++ks)
#pragma unroll
      for (int j = 0; j < 4; ++j) {
        int r = j * 16 + lr;
        kb[ks][j] = *(const s16x8*)((const char*)lsK[cur] + r * 128 +
                                    ((ks * 64 + lh * 16) ^ ((r & 7) << 4)));
      }

    if (it + 1 < ntile) stageKV(cur ^ 1, tB + it + 1);

    // S^T = K Q^T : st[i][j] reg q = S[q0+i*16+lr][key j*16+lh*4+q]
    f32x4 st[2][4];
#pragma unroll
    for (int i = 0; i < 2; ++i)
#pragma unroll
      for (int j = 0; j < 4; ++j) st[i][j] = f32x4{0.f, 0.f, 0.f, 0.f};
    __builtin_amdgcn_s_setprio(1);
#pragma unroll
    for (int ks = 0; ks < 2; ++ks)
#pragma unroll
      for (int j = 0; j < 4; ++j)
#pragma unroll
        for (int i = 0; i < 2; ++i)
          st[i][j] = mfma16(kb[ks][j], qf[i][ks], st[i][j]);
    __builtin_amdgcn_s_setprio(0);

    // softmax (per-lane: 2 rows, 16 in-lane keys each; 2 shfls per row)
    float mx[2];
    bool need = false;
#pragma unroll
    for (int i = 0; i < 2; ++i) {
      float a0 = fmaxf(fmaxf(st[i][0][0], st[i][0][1]), fmaxf(st[i][0][2], st[i][0][3]));
      float a1 = fmaxf(fmaxf(st[i][1][0], st[i][1][1]), fmaxf(st[i][1][2], st[i][1][3]));
      float a2 = fmaxf(fmaxf(st[i][2][0], st[i][2][1]), fmaxf(st[i][2][2], st[i][2][3]));
      float a3 = fmaxf(fmaxf(st[i][3][0], st[i][3][1]), fmaxf(st[i][3][2], st[i][3][3]));
      float m = fmaxf(fmaxf(a0, a1), fmaxf(a2, a3));
      m = fmaxf(m, __shfl_xor(m, 16));
      m = fmaxf(m, __shfl_xor(m, 32));
      mx[i] = m;
      need = need || (m > mrow[i] + 11.f);
    }
    if (__any(need)) {
#pragma unroll
      for (int i = 0; i < 2; ++i) {
        float mn = fmaxf(mrow[i], mx[i]);
        float al = exp2f(mrow[i] - mn);
        mrow[i] = mn;
        lsum[i] *= al;
#pragma unroll
        for (int d = 0; d < 4; ++d)
#pragma unroll
          for (int q = 0; q < 4; ++q) oacc[i][d][q] *= al;
      }
    }
#pragma unroll
    for (int i = 0; i < 2; ++i) {
      float ps = 0.f;
#pragma unroll
      for (int j = 0; j < 4; ++j) {
        float p0 = exp2f(st[i][j][0] - mrow[i]);
        float p1 = exp2f(st[i][j][1] - mrow[i]);
        float p2 = exp2f(st[i][j][2] - mrow[i]);
        float p3 = exp2f(st[i][j][3] - mrow[i]);
        ps += (p0 + p1) + (p2 + p3);
        u32x2 pk;
        pk.x = cvt_pk_bf16(p0, p1);
        pk.y = cvt_pk_bf16(p2, p3);
        *(u32x2*)((char*)lsP[wave] + (i * 16 + lr) * 128 +
                  ((j * 32 + lh * 8) ^ ((lr & 7) << 4))) = pk;
      }
      ps += __shfl_xor(ps, 16);
      ps += __shfl_xor(ps, 32);
      lsum[i] += ps;
    }

    // O^T += V^T P : vb loaded once, used for both i-units
    __builtin_amdgcn_s_setprio(1);
#pragma unroll
    for (int ks = 0; ks < 2; ++ks) {
      s16x8 pa0 = *(const s16x8*)((const char*)lsP[wave] + lr * 128 +
                                  ((ks * 64 + lh * 16) ^ ((lr & 7) << 4)));
      s16x8 pa1 = *(const s16x8*)((const char*)lsP[wave] + (16 + lr) * 128 +
                                  ((ks * 64 + lh * 16) ^ ((lr & 7) << 4)));
#pragma unroll
      for (int d = 0; d < 4; ++d) {
        int r = d * 16 + lr;
        s16x8 vb = *(const s16x8*)((const char*)lsV[cur] + r * 128 +
                                   ((ks * 64 + lh * 16) ^ ((r & 7) << 4)));
        oacc[0][d] = mfma16(vb, pa0, oacc[0][d]);
        oacc[1][d] = mfma16(vb, pa1, oacc[1][d]);
      }
    }
    __builtin_amdgcn_s_setprio(0);
  }

  // epilogue: unnormalized partial O (f32) + (m, l)
#pragma unroll
  for (int i = 0; i < 2; ++i) {
    int s = q0 + i * 16 + lr;
    size_t r = ((size_t)z * nbh + bh) * 2048 + s;
#pragma unroll
    for (int d = 0; d < 4; ++d)
      *(f32x4*)(Op + r * 64 + d * 16 + lh * 4) = oacc[i][d];
    if (lh == 0) { ml[r * 2] = mrow[i]; ml[r * 2 + 1] = lsum[i]; }
  }
}

// combine 2 KV-split partials -> ctx (bf16, [b][s][h*64+d] layout)
__global__ __launch_bounds__(256) void attn_combine(const float* __restrict__ Op,
                                                    const float* __restrict__ ml,
                                                    u16* __restrict__ ctx, int nbh) {
  size_t i = (size_t)blockIdx.x * 256 + threadIdx.x;   // nbh*2048*16 threads
  int d4 = (int)(i & 15);
  size_t rs = i >> 4;
  size_t zs = (size_t)nbh * 2048;
  float m0 = ml[rs * 2],        l0 = ml[rs * 2 + 1];
  float m1 = ml[(zs + rs) * 2], l1 = ml[(zs + rs) * 2 + 1];
  float mx = fmaxf(m0, m1);
  float a0 = exp2f(m0 - mx), a1 = exp2f(m1 - mx);
  float inv = 1.f / (l0 * a0 + l1 * a1);
  a0 *= inv; a1 *= inv;
  f32x4 o0 = *(const f32x4*)(Op + rs * 64 + d4 * 4);
  f32x4 o1 = *(const f32x4*)(Op + (zs + rs) * 64 + d4 * 4);
  int bh = (int)(rs >> 11), s = (int)(rs & 2047);
  int b = bh / 12, h = bh - b * 12;
  u16x4 r;
#pragma unroll
  for (int k = 0; k < 4; ++k) r[k] = f2b(o0[k] * a0 + o1[k] * a1);
  *(u16x4*)(ctx + ((size_t)(b * 2048 + s)) * 768 + h * 64 + d4 * 4) = r;
}

// ---------------------------------------------------------------------------
// residual + LayerNorm over 768; yin = sum of NP partials (split-K GEMM out);
// optionally emit bf16 copy for next GEMM
// ---------------------------------------------------------------------------
template <int NP>
__global__ __launch_bounds__(256) void resid_ln(const float* __restrict__ xin,
                                                const float* __restrict__ yp,
                                                size_t pstride,
                                                const float* __restrict__ gamma,
                                                const float* __restrict__ beta,
                                                float* __restrict__ outf,
                                                u16* __restrict__ outb) {
  const int row = blockIdx.x, t = threadIdx.x;
  const size_t base = (size_t)row * 768;
  float v[3], s = 0.f, s2 = 0.f;
#pragma unroll
  for (int k = 0; k < 3; ++k) {
    int c = t + k * 256;
    float val = xin[base + c];
#pragma unroll
    for (int p = 0; p < NP; ++p) val += yp[p * pstride + base + c];
    v[k] = val; s += val; s2 += val * val;
  }
#pragma unroll
  for (int off = 32; off > 0; off >>= 1) {
    s += __shfl_down(s, off, 64);
    s2 += __shfl_down(s2, off, 64);
  }
  __shared__ float red[8];
  int lane = t & 63, wave = t >> 6;
  if (lane == 0) { red[wave] = s; red[4 + wave] = s2; }
  __syncthreads();
  s = red[0] + red[1] + red[2] + red[3];
  s2 = red[4] + red[5] + red[6] + red[7];
  const float inv = 1.f / 768.f;
  float mu = s * inv;
  float var = fmaxf(s2 * inv - mu * mu, 0.f);
  float rs = rsqrtf(var + 1e-5f);
#pragma unroll
  for (int k = 0; k < 3; ++k) {
    int c = t + k * 256;
    float o = (v[k] - mu) * rs * gamma[c] + beta[c];
    if (outf) outf[base + c] = o;
    if (outb) outb[base + c] = f2b(o);
  }
}

// ---------------------------------------------------------------------------
extern "C" void kernel_launch(void* const* d_in, const int* in_sizes, int n_in,
                              void* d_out, int out_size, void* d_ws, size_t ws_size,
                              hipStream_t stream) {
  const float* x   = (const float*)d_in[0];
  const float* Wq  = (const float*)d_in[1];
  const float* bq  = (const float*)d_in[2];
  const float* Wk  = (const float*)d_in[3];
  const float* bk  = (const float*)d_in[4];
  const float* Wv  = (const float*)d_in[5];
  const float* bv  = (const float*)d_in[6];
  const float* Wo  = (const float*)d_in[7];
  const float* bo  = (const float*)d_in[8];
  const float* W1  = (const float*)d_in[9];
  const float* b1  = (const float*)d_in[10];
  const float* W2  = (const float*)d_in[11];
  const float* b2  = (const float*)d_in[12];
  const float* g1  = (const float*)d_in[13];
  const float* be1 = (const float*)d_in[14];
  const float* g2  = (const float*)d_in[15];
  const float* be2 = (const float*)d_in[16];
  float* out = (float*)d_out;

  const int M = in_sizes[0] / 768;   // 4096 tokens
  const int B = M / 2048;            // 2
  const int nbh = B * 12;

  char* ws = (char*)d_ws;
  size_t off = 0;
  auto alloc = [&](size_t bytes) -> void* {
    void* p = ws + off;
    off += (bytes + 255) & ~(size_t)255;
    return p;
  };
  u16*   Wqkv_t = (u16*)alloc((size_t)2304 * 768 * 2);
  u16*   Wo_t   = (u16*)alloc((size_t)768 * 768 * 2);
  u16*   W1_t   = (u16*)alloc((size_t)3072 * 768 * 2);
  u16*   W2_t   = (u16*)alloc((size_t)768 * 3072 * 2);
  float* bqkv   = (float*)alloc(2304 * 4);
  u16*   Xb     = (u16*)alloc((size_t)M * 768 * 2);      // reused as ctx
  u16*   Qh     = (u16*)alloc((size_t)M * 768 * 2);      // later: proj partials
  u16*   Kh     = (u16*)alloc((size_t)M * 768 * 2);
  u16*   Vh     = (u16*)alloc((size_t)M * 768 * 2);
  u16*   Vt     = (u16*)alloc((size_t)M * 768 * 2);

  size_t opElems = (size_t)2 * nbh * 2048 * 64;
  size_t mlElems = (size_t)2 * nbh * 2048 * 2;
  size_t attnBytes = (opElems + mlElems) * 4;
  size_t pstride = (size_t)M * 768;                      // elems per partial
  size_t fixedRest = pstride * 4 /*x1f*/ + pstride * 2 /*x1b*/ +
                     (size_t)M * 3072 * 2 /*hb*/ + 4096;
  size_t need4 = off + ((pstride * 4 * 4 > attnBytes ? pstride * 4 * 4 : attnBytes)) + fixedRest;
  const int SPLIT2 = (ws_size >= need4) ? 4 : 2;
  size_t regionBytes = pstride * 4 * SPLIT2;
  if (regionBytes < attnBytes) regionBytes = attnBytes;
  float* region = (float*)alloc(regionBytes);
  float* Op   = region;
  float* ml   = region + opElems;
  float* ffnPart  = region;                    // alive after attn_combine
  float* projPart = (float*)Qh;                // alive after attn (2 partials)
  float* x1f  = (float*)alloc(pstride * 4);
  u16*   x1b  = (u16*)alloc(pstride * 2);
  u16*   hb   = (u16*)alloc((size_t)M * 3072 * 2);
  u16*   ctx  = Xb;

  dim3 tb(32, 8);
  const int convBlocks = (M * 768) / 1024;
  prep<<<6912 + convBlocks + 9, tb, 0, stream>>>(
      Wq, Wk, Wv, Wo, W1, W2, bq, bk, bv, x,
      Wqkv_t, Wo_t, W1_t, W2_t, bqkv, Xb, convBlocks);

  gemm_bt<2><<<dim3(2304 / 128, M / 128), 256, 0, stream>>>(
      Xb, Wqkv_t, bqkv, nullptr, nullptr, Qh, Kh, Vh, M, 2304, 768, 768);

  transpose_v<<<dim3(2, 64, nbh), tb, 0, stream>>>(Vh, Vt);

  attn<<<dim3(16, nbh, 2), 256, 0, stream>>>(Qh, Kh, Vt, Op, ml, nbh, 16);
  attn_combine<<<nbh * 128, 256, 0, stream>>>(Op, ml, ctx, nbh);

  gemm_bt<0><<<dim3(768 / 128, M / 128, 2), 256, 0, stream>>>(
      ctx, Wo_t, bo, projPart, nullptr, nullptr, nullptr, nullptr, M, 768, 768, 384);

  resid_ln<2><<<M, 256, 0, stream>>>(x, projPart, pstride, g1, be1, x1f, x1b);

  gemm_bt<1><<<dim3(3072 / 128, M / 128), 256, 0, stream>>>(
      x1b, W1_t, b1, nullptr, hb, nullptr, nullptr, nullptr, M, 3072, 768, 768);

  if (SPLIT2 == 4) {
    gemm_bt<0><<<dim3(768 / 128, M / 128, 4), 256, 0, stream>>>(
        hb, W2_t, b2, ffnPart, nullptr, nullptr, nullptr, nullptr, M, 768, 3072, 768);
    resid_ln<4><<<M, 256, 0, stream>>>(x1f, ffnPart, pstride, g2, be2, out, nullptr);
  } else {
    gemm_bt<0><<<dim3(768 / 128, M / 128, 2), 256, 0, stream>>>(
        hb, W2_t, b2, ffnPart, nullptr, nullptr, nullptr, nullptr, M, 768, 3072, 1536);
    resid_ln<2><<<M, 256, 0, stream>>>(x1f, ffnPart, pstride, g2, be2, out, nullptr);
  }
}